// Round 13
// baseline (274.531 us; speedup 1.0000x reference)
//
#include <hip/hip_runtime.h>
#include <math.h>

#define N_NODES 50000
#define F_IN    512
#define H1      8
#define C1      8
#define D1      64    // H1*C1
#define OUT_C   128
#define NEG     0.2f

#define SCHUNK  256
#define SNBLK   ((N_NODES + SCHUNK - 1)/SCHUNK)   // 196

#define NHB      256    // histogram/scatter blocks
#define HTHREADS 1024
#define HALF     25000  // nodes per LDS pass
#define HWORDS   12500  // packed u32 words per pass (2 u16 counters each)

using bf16x8 = __attribute__((ext_vector_type(8))) short;
using f32x4  = __attribute__((ext_vector_type(4))) float;
typedef unsigned short u16;
typedef unsigned int   u32;

__device__ __forceinline__ float leaky(float x){
    return fmaxf(x, 0.f) + NEG * fminf(x, 0.f);
}
__device__ __forceinline__ u16 f2bf(float f){           // RNE
    u32 u = __float_as_uint(f);
    u32 r = u + 0x7FFF + ((u>>16)&1);
    return (u16)(r>>16);
}
__device__ __forceinline__ float bf2f(u16 h){ return __uint_as_float(((u32)h)<<16); }

// split-convert 8 f32 -> bf16 hi + bf16 residual
__device__ __forceinline__ void cvt8(const float4& a, const float4& b, bf16x8& hi, bf16x8& lo){
    u16 h0=f2bf(a.x),h1=f2bf(a.y),h2=f2bf(a.z),h3=f2bf(a.w);
    u16 h4=f2bf(b.x),h5=f2bf(b.y),h6=f2bf(b.z),h7=f2bf(b.w);
    hi = (bf16x8){(short)h0,(short)h1,(short)h2,(short)h3,
                  (short)h4,(short)h5,(short)h6,(short)h7};
    lo = (bf16x8){(short)f2bf(a.x-bf2f(h0)),(short)f2bf(a.y-bf2f(h1)),
                  (short)f2bf(a.z-bf2f(h2)),(short)f2bf(a.w-bf2f(h3)),
                  (short)f2bf(b.x-bf2f(h4)),(short)f2bf(b.y-bf2f(h5)),
                  (short)f2bf(b.z-bf2f(h6)),(short)f2bf(b.w-bf2f(h7))};
}

// ---------------------------------------------------------------- per-block LDS histogram -> histmat[blk][node] (u16)
__global__ __launch_bounds__(1024) void k_histB(const int* __restrict__ dst_a, int E, int CE,
                                                u16* __restrict__ histmat){
    __shared__ u32 lcnt[HWORDS];
    const int blk = blockIdx.x;
    const int i0 = blk*CE;
    const int i1 = min(i0+CE, E + N_NODES);
    for (int p=0;p<2;p++){
        for (int w=threadIdx.x; w<HWORDS; w+=HTHREADS) lcnt[w]=0;
        __syncthreads();
        const int lo = p*HALF, hi = lo+HALF;
        for (int i=i0+(int)threadIdx.x; i<i1; i+=HTHREADS){
            int d = (i<E)? dst_a[i] : (i-E);
            if (d>=lo && d<hi){
                int dd = d - lo;
                atomicAdd(&lcnt[dd>>1], 1u<<((dd&1)*16));
            }
        }
        __syncthreads();
        u16* dst = histmat + (size_t)blk*N_NODES + lo;
        for (int w=threadIdx.x; w<HWORDS; w+=HTHREADS){
            *(u32*)(dst + 2*w) = lcnt[w];
        }
        __syncthreads();
    }
}

// ---------------------------------------------------------------- column scan: histmat -> per-block exclusive prefix (u16), cnt
__global__ __launch_bounds__(256) void k_colscan(u16* __restrict__ histmat, int* __restrict__ cnt){
    int n = blockIdx.x*256 + threadIdx.x;
    if (n >= N_NODES) return;
    u32 run = 0;
    u16* p = histmat + n;
    #pragma unroll 4
    for (int b=0;b<NHB;b++){
        u32 v = p[(size_t)b*N_NODES];
        p[(size_t)b*N_NODES] = (u16)run;
        run += v;
    }
    cnt[n] = (int)run;
}

// ---------------------------------------------------------------- 3-phase scan over cnt -> rowptr
__global__ __launch_bounds__(256) void k_scanA(const int* __restrict__ cnt, int* bsum){
    __shared__ int sm[256];
    int idx = blockIdx.x*256 + threadIdx.x;
    int v = (idx < N_NODES) ? cnt[idx] : 0;
    sm[threadIdx.x] = v; __syncthreads();
    for (int off=128; off>0; off>>=1){
        if (threadIdx.x < off) sm[threadIdx.x] += sm[threadIdx.x+off];
        __syncthreads();
    }
    if (threadIdx.x==0) bsum[blockIdx.x] = sm[0];
}

__global__ __launch_bounds__(256) void k_scanB(const int* __restrict__ bsum, int* boff, int* rowptr){
    __shared__ int sm[256];
    int t = threadIdx.x;
    int v = (t < SNBLK) ? bsum[t] : 0;
    sm[t]=v; __syncthreads();
    for (int off=1; off<256; off<<=1){
        int u = (t>=off)? sm[t-off] : 0;
        __syncthreads();
        sm[t]+=u; __syncthreads();
    }
    if (t < SNBLK) boff[t] = sm[t] - v;       // exclusive
    if (t==255) rowptr[N_NODES] = sm[255];    // total = E + N
}

__global__ __launch_bounds__(256) void k_scanC(const int* __restrict__ cnt, const int* __restrict__ boff,
                                               int* rowptr){
    __shared__ int sm[256];
    int idx = blockIdx.x*256 + threadIdx.x;
    int t = threadIdx.x;
    int v = (idx<N_NODES)? cnt[idx] : 0;
    sm[t]=v; __syncthreads();
    for (int off=1; off<256; off<<=1){
        int u = (t>=off)? sm[t-off] : 0;
        __syncthreads();
        sm[t]+=u; __syncthreads();
    }
    if (idx<N_NODES){
        rowptr[idx] = boff[blockIdx.x] + sm[t] - v;
    }
}

// ---------------------------------------------------------------- atomic-free scatter (LDS local ranks)
__global__ __launch_bounds__(1024) void k_scatterB(const int* __restrict__ src_a, const int* __restrict__ dst_a,
                                                   int E, int CE,
                                                   const u16* __restrict__ histmat, const int* __restrict__ rowptr,
                                                   int* __restrict__ srcs){
    __shared__ u32 lcnt[HWORDS];
    const int blk = blockIdx.x;
    const int i0 = blk*CE;
    const int i1 = min(i0+CE, E + N_NODES);
    const u16* __restrict__ pb = histmat + (size_t)blk*N_NODES;
    for (int p=0;p<2;p++){
        for (int w=threadIdx.x; w<HWORDS; w+=HTHREADS) lcnt[w]=0;
        __syncthreads();
        const int lo = p*HALF, hi = lo+HALF;
        for (int i=i0+(int)threadIdx.x; i<i1; i+=HTHREADS){
            int s, d;
            if (i<E){ s=src_a[i]; d=dst_a[i]; } else { s=d=i-E; }
            if (d>=lo && d<hi){
                int dd = d - lo;
                u32 old = atomicAdd(&lcnt[dd>>1], 1u<<((dd&1)*16));
                u32 rank = (old >> ((dd&1)*16)) & 0xFFFFu;
                int pos = rowptr[d] + (int)pb[d] + (int)rank;
                srcs[pos] = s;
            }
        }
        __syncthreads();
    }
}

// ---------------------------------------------------------------- W1 split/transpose: whiT/wloT [64 col][512 k] bf16
__global__ void k_cvtW(const float* __restrict__ W1, u16* __restrict__ whiT, u16* __restrict__ wloT){
    int i = blockIdx.x*blockDim.x + threadIdx.x;   // 0..32767
    if (i >= F_IN*D1) return;
    int k = i >> 6, col = i & 63;
    float v = W1[i];
    u16 hi = f2bf(v);
    float lo = v - bf2f(hi);
    whiT[col*F_IN + k] = hi;
    wloT[col*F_IN + k] = f2bf(lo);
}

// ---------------------------------------------------------------- W2 split/transpose: [128 col][64 k] bf16
__global__ void k_cvtW2(const float* __restrict__ W2, u16* __restrict__ w2hiT, u16* __restrict__ w2loT){
    int i = blockIdx.x*blockDim.x + threadIdx.x;   // 0..8191
    if (i >= D1*OUT_C) return;
    int k = i >> 7, col = i & 127;
    float v = W2[i];
    u16 hi = f2bf(v);
    float lo = v - bf2f(hi);
    w2hiT[col*D1 + k] = hi;
    w2loT[col*D1 + k] = f2bf(lo);
}

// ---------------------------------------------------------------- GEMM1 via MFMA, LDS-free (direct A fragments, split-bf16)
// wave computes 16 rows x 64 cols; lane(lr,lq): A row lr, k-seg lq*8
__global__ __launch_bounds__(256) void k_gemm1(
        const float* __restrict__ x,
        const u16* __restrict__ whiT, const u16* __restrict__ wloT,
        const float* __restrict__ att_src, const float* __restrict__ att_dst,
        u16* __restrict__ h1b, float* __restrict__ asrc, float* __restrict__ adst){
    const int tid = threadIdx.x;
    const int wid = tid>>6, l = tid&63;
    const int lq = l>>4, lr = l&15;
    const int rowbase = blockIdx.x*64;
    const int arow = min(rowbase + wid*16 + lr, N_NODES-1);
    const float* __restrict__ xrow = x + (size_t)arow*F_IN + lq*8;

    f32x4 acc[4];
    #pragma unroll
    for (int n=0;n<4;n++) acc[n] = (f32x4){0.f,0.f,0.f,0.f};

    // prefetch K-step 0 (two kt segments of 32B each)
    float4 p0 = *(const float4*)(xrow);
    float4 p1 = *(const float4*)(xrow+4);
    float4 p2 = *(const float4*)(xrow+32);
    float4 p3 = *(const float4*)(xrow+36);

    for (int ks=0; ks<8; ks++){
        bf16x8 ahi0, alo0, ahi1, alo1;
        cvt8(p0, p1, ahi0, alo0);
        cvt8(p2, p3, ahi1, alo1);
        if (ks < 7){
            const float* nx = xrow + (ks+1)*64;
            p0 = *(const float4*)(nx);
            p1 = *(const float4*)(nx+4);
            p2 = *(const float4*)(nx+32);
            p3 = *(const float4*)(nx+36);
        }
        const int k0 = ks*64;
        #pragma unroll
        for (int n=0;n<4;n++){
            const size_t wo = (size_t)(n*16+lr)*F_IN + k0 + lq*8;
            bf16x8 bhi0 = *(const bf16x8*)(whiT + wo);
            bf16x8 blo0 = *(const bf16x8*)(wloT + wo);
            acc[n] = __builtin_amdgcn_mfma_f32_16x16x32_bf16(ahi0, bhi0, acc[n], 0,0,0);
            acc[n] = __builtin_amdgcn_mfma_f32_16x16x32_bf16(ahi0, blo0, acc[n], 0,0,0);
            acc[n] = __builtin_amdgcn_mfma_f32_16x16x32_bf16(alo0, bhi0, acc[n], 0,0,0);
            bf16x8 bhi1 = *(const bf16x8*)(whiT + wo + 32);
            bf16x8 blo1 = *(const bf16x8*)(wloT + wo + 32);
            acc[n] = __builtin_amdgcn_mfma_f32_16x16x32_bf16(ahi1, bhi1, acc[n], 0,0,0);
            acc[n] = __builtin_amdgcn_mfma_f32_16x16x32_bf16(ahi1, blo1, acc[n], 0,0,0);
            acc[n] = __builtin_amdgcn_mfma_f32_16x16x32_bf16(alo1, bhi1, acc[n], 0,0,0);
        }
    }

    // epilogue: C/D layout col=lane&15, row=(lane>>4)*4+i  [HW-verified]
    #pragma unroll
    for (int n=0;n<4;n++){
        int col = n*16 + lr;
        float as_w = att_src[col], ad_w = att_dst[col];
        #pragma unroll
        for (int i=0;i<4;i++){
            int node = rowbase + wid*16 + lq*4 + i;
            float v = acc[n][i];
            float s = v*as_w, d = v*ad_w;
            s += __shfl_xor(s,1); d += __shfl_xor(d,1);
            s += __shfl_xor(s,2); d += __shfl_xor(d,2);
            s += __shfl_xor(s,4); d += __shfl_xor(d,4);
            if (node < N_NODES){
                h1b[(size_t)node*D1 + col] = f2bf(v);
                if ((l&7)==0){
                    int head = col>>3;
                    asrc[node*H1 + head] = s;
                    adst[node*H1 + head] = d;
                }
            }
        }
    }
}

// ---------------------------------------------------------------- layer1 aggregation: 8 edges per gather instruction
__global__ __launch_bounds__(256) void k_agg1(
        const int* __restrict__ rowptr, const int* __restrict__ srcs,
        const float* __restrict__ asrc1, const float* __restrict__ adst1,
        const u16* __restrict__ h1b, float* __restrict__ out1){
    const int node = blockIdx.x*4 + (threadIdx.x>>6);
    const int lane = threadIdx.x & 63;
    const int g = lane >> 3;
    const int p = lane & 7;
    const int r0 = __builtin_amdgcn_readfirstlane(rowptr[node]);
    const int r1 = __builtin_amdgcn_readfirstlane(rowptr[node+1]);
    const float ad = adst1[node*H1 + p];
    float a0=0,a1=0,a2=0,a3=0,a4=0,a5=0,a6=0,a7=0, den=0;
    for (int base=r0; base<r1; base+=64){
        int eidx = base + lane;
        int sl = srcs[eidx < r1 ? eidx : (r1-1)];
        const int m = min(64, r1-base);
        for (int k=0; k*8 < m; k++){
            int e = k*8 + g;
            int s = __shfl(sl, e);
            float w = (base + e < r1) ? __expf(leaky(asrc1[s*H1 + p] + ad)) : 0.f;
            uint4 pv = *(const uint4*)(h1b + (size_t)s*D1 + p*8);
            a0 += w*bf2f((u16)(pv.x&0xFFFFu)); a1 += w*bf2f((u16)(pv.x>>16));
            a2 += w*bf2f((u16)(pv.y&0xFFFFu)); a3 += w*bf2f((u16)(pv.y>>16));
            a4 += w*bf2f((u16)(pv.z&0xFFFFu)); a5 += w*bf2f((u16)(pv.z>>16));
            a6 += w*bf2f((u16)(pv.w&0xFFFFu)); a7 += w*bf2f((u16)(pv.w>>16));
            den += w;
        }
    }
    #pragma unroll
    for (int off=8; off<64; off<<=1){
        a0 += __shfl_xor(a0,off); a1 += __shfl_xor(a1,off);
        a2 += __shfl_xor(a2,off); a3 += __shfl_xor(a3,off);
        a4 += __shfl_xor(a4,off); a5 += __shfl_xor(a5,off);
        a6 += __shfl_xor(a6,off); a7 += __shfl_xor(a7,off);
        den += __shfl_xor(den,off);
    }
    if (g == 0){
        float inv = 1.f/den;
        float* o = out1 + (size_t)node*D1 + p*8;
        *(float4*)(o)   = make_float4(a0*inv, a1*inv, a2*inv, a3*inv);
        *(float4*)(o+4) = make_float4(a4*inv, a5*inv, a6*inv, a7*inv);
    }
}

// ---------------------------------------------------------------- GEMM2 via MFMA: h2 = elu(out1+b1) @ W2 (+alpha epilogue); h2 stored bf16
__global__ __launch_bounds__(256) void k_gemm2(
        const float* __restrict__ out1, const float* __restrict__ b1,
        const u16* __restrict__ w2hiT, const u16* __restrict__ w2loT,
        const float* __restrict__ att_src2, const float* __restrict__ att_dst2,
        u16* __restrict__ h2b, float* __restrict__ asrc2, float* __restrict__ adst2){
    __shared__ u16 Ahi[64*64];   // 8 KB, XOR-swizzled
    __shared__ u16 Alo[64*64];   // 8 KB
    const int tid = threadIdx.x;
    const int wid = tid>>6, l = tid&63;
    const int lq = l>>4, lr = l&15;
    const int rowbase = blockIdx.x*64;

    #pragma unroll
    for (int q=0;q<4;q++){
        int p = tid + 256*q;
        int r = p>>4, kseg = p&15;
        int grow = min(rowbase + r, N_NODES-1);
        float4 v = *(const float4*)(out1 + (size_t)grow*D1 + kseg*4);
        float4 bb = *(const float4*)(b1 + kseg*4);
        float a0 = v.x+bb.x, a1 = v.y+bb.y, a2 = v.z+bb.z, a3 = v.w+bb.w;
        a0 = a0>0.f ? a0 : (__expf(a0)-1.f);
        a1 = a1>0.f ? a1 : (__expf(a1)-1.f);
        a2 = a2>0.f ? a2 : (__expf(a2)-1.f);
        a3 = a3>0.f ? a3 : (__expf(a3)-1.f);
        u16 h0=f2bf(a0), h1v=f2bf(a1), h2v=f2bf(a2), h3v=f2bf(a3);
        u16 e0=f2bf(a0-bf2f(h0)), e1=f2bf(a1-bf2f(h1v)),
            e2=f2bf(a2-bf2f(h2v)), e3=f2bf(a3-bf2f(h3v));
        int boff = (r*128 + kseg*8) ^ ((r&7)<<4);
        *(ushort4*)((char*)Ahi + boff) = make_ushort4(h0,h1v,h2v,h3v);
        *(ushort4*)((char*)Alo + boff) = make_ushort4(e0,e1,e2,e3);
    }
    __syncthreads();

    const int arow = wid*16 + lr;
    bf16x8 ahi[2], alo[2];
    #pragma unroll
    for (int kt=0;kt<2;kt++){
        int boff = (arow*128 + kt*64 + lq*16) ^ ((arow&7)<<4);
        ahi[kt] = *(const bf16x8*)((const char*)Ahi + boff);
        alo[kt] = *(const bf16x8*)((const char*)Alo + boff);
    }

    f32x4 acc[8];
    #pragma unroll
    for (int n=0;n<8;n++) acc[n] = (f32x4){0.f,0.f,0.f,0.f};
    #pragma unroll
    for (int n=0;n<8;n++){
        #pragma unroll
        for (int kt=0;kt<2;kt++){
            const size_t wo = (size_t)(n*16+lr)*D1 + kt*32 + lq*8;
            bf16x8 bhi = *(const bf16x8*)(w2hiT + wo);
            bf16x8 blo = *(const bf16x8*)(w2loT + wo);
            acc[n] = __builtin_amdgcn_mfma_f32_16x16x32_bf16(ahi[kt], bhi, acc[n], 0,0,0);
            acc[n] = __builtin_amdgcn_mfma_f32_16x16x32_bf16(ahi[kt], blo, acc[n], 0,0,0);
            acc[n] = __builtin_amdgcn_mfma_f32_16x16x32_bf16(alo[kt], bhi, acc[n], 0,0,0);
        }
    }

    float aw[8], dw[8];
    #pragma unroll
    for (int n=0;n<8;n++){ aw[n]=att_src2[n*16+lr]; dw[n]=att_dst2[n*16+lr]; }
    #pragma unroll
    for (int i=0;i<4;i++){
        int node = rowbase + wid*16 + lq*4 + i;
        bool ok = node < N_NODES;
        float s = 0.f, d = 0.f;
        #pragma unroll
        for (int n=0;n<8;n++){
            float v = acc[n][i];
            s = fmaf(v, aw[n], s);
            d = fmaf(v, dw[n], d);
            if (ok) h2b[(size_t)node*OUT_C + n*16 + lr] = f2bf(v);
        }
        s += __shfl_xor(s,1); d += __shfl_xor(d,1);
        s += __shfl_xor(s,2); d += __shfl_xor(d,2);
        s += __shfl_xor(s,4); d += __shfl_xor(d,4);
        s += __shfl_xor(s,8); d += __shfl_xor(d,8);
        if (ok && lr==0){ asrc2[node]=s; adst2[node]=d; }
    }
}

// ---------------------------------------------------------------- layer2 aggregation: 4 edges per gather instruction
__global__ __launch_bounds__(256) void k_agg2(
        const int* __restrict__ rowptr, const int* __restrict__ srcs,
        const float* __restrict__ asrc2, const float* __restrict__ adst2,
        const u16* __restrict__ h2b, const float* __restrict__ b2,
        float* __restrict__ out){
    const int node = blockIdx.x*4 + (threadIdx.x>>6);
    const int lane = threadIdx.x & 63;
    const int g = lane >> 4;
    const int p = lane & 15;
    const int r0 = __builtin_amdgcn_readfirstlane(rowptr[node]);
    const int r1 = __builtin_amdgcn_readfirstlane(rowptr[node+1]);
    const float ad = adst2[node];
    float a0=0,a1=0,a2=0,a3=0,a4=0,a5=0,a6=0,a7=0, den=0;
    for (int base=r0; base<r1; base+=64){
        int eidx = base + lane;
        int sl = srcs[eidx < r1 ? eidx : (r1-1)];
        float wl = (eidx < r1) ? __expf(leaky(asrc2[sl] + ad)) : 0.f;
        const int m = min(64, r1-base);
        for (int k=0; k*4 < m; k++){
            int e = k*4 + g;
            int   s = __shfl(sl, e);
            float w = __shfl(wl, e);      // 0 for padded slots
            uint4 pv = *(const uint4*)(h2b + (size_t)s*OUT_C + p*8);
            a0 += w*bf2f((u16)(pv.x&0xFFFFu)); a1 += w*bf2f((u16)(pv.x>>16));
            a2 += w*bf2f((u16)(pv.y&0xFFFFu)); a3 += w*bf2f((u16)(pv.y>>16));
            a4 += w*bf2f((u16)(pv.z&0xFFFFu)); a5 += w*bf2f((u16)(pv.z>>16));
            a6 += w*bf2f((u16)(pv.w&0xFFFFu)); a7 += w*bf2f((u16)(pv.w>>16));
            den += w;
        }
    }
    #pragma unroll
    for (int off=16; off<64; off<<=1){
        a0 += __shfl_xor(a0,off); a1 += __shfl_xor(a1,off);
        a2 += __shfl_xor(a2,off); a3 += __shfl_xor(a3,off);
        a4 += __shfl_xor(a4,off); a5 += __shfl_xor(a5,off);
        a6 += __shfl_xor(a6,off); a7 += __shfl_xor(a7,off);
        den += __shfl_xor(den,off);
    }
    if (g == 0){
        float inv = 1.f/den;
        const float* bb = b2 + p*8;
        float* o = out + (size_t)node*OUT_C + p*8;
        *(float4*)(o)   = make_float4(a0*inv+bb[0], a1*inv+bb[1], a2*inv+bb[2], a3*inv+bb[3]);
        *(float4*)(o+4) = make_float4(a4*inv+bb[4], a5*inv+bb[5], a6*inv+bb[6], a7*inv+bb[7]);
    }
}

// ---------------------------------------------------------------- launch
extern "C" void kernel_launch(void* const* d_in, const int* in_sizes, int n_in,
                              void* d_out, int out_size, void* d_ws, size_t ws_size,
                              hipStream_t stream) {
    const float* x        = (const float*)d_in[0];
    const int*   edge     = (const int*)  d_in[1];
    const float* W1       = (const float*)d_in[2];
    const float* att_src1 = (const float*)d_in[3];
    const float* att_dst1 = (const float*)d_in[4];
    const float* b1       = (const float*)d_in[5];
    const float* W2       = (const float*)d_in[6];
    const float* att_src2 = (const float*)d_in[7];
    const float* att_dst2 = (const float*)d_in[8];
    const float* b2       = (const float*)d_in[9];
    float* out = (float*)d_out;

    const int E  = in_sizes[1] / 2;
    const int ET = E + N_NODES;
    const int CE = (ET + NHB - 1) / NHB;
    const int* src_a = edge;
    const int* dst_a = edge + E;

    // workspace layout (element counts sized for f32 regions; h1/h2 use half as u16)
    float* ws = (float*)d_ws;
    float* h1f   = ws;                            // N*64 f32 region -> used as u16 h1b
    float* asrc1 = h1f   + (size_t)N_NODES*D1;    // N*8
    float* adst1 = asrc1 + (size_t)N_NODES*H1;    // N*8
    float* out1  = adst1 + (size_t)N_NODES*H1;    // N*64
    float* h2f   = out1  + (size_t)N_NODES*D1;    // N*128 f32 region -> used as u16 h2b
    float* asrc2 = h2f   + (size_t)N_NODES*OUT_C; // N
    float* adst2 = asrc2 + N_NODES;               // N
    int*   cnt    = (int*)(adst2 + N_NODES);      // N
    int*   rowptr = cnt    + N_NODES;             // N+4
    int*   srcs   = rowptr + (N_NODES+4);         // ET
    int*   bsum   = srcs   + ET;                  // 256
    int*   boff   = bsum   + 256;                 // 256
    u16*   histmat= (u16*)(boff + 256);           // NHB*N u16 (25.6 MB; dead after scatterB)
    u16*   whiT   = histmat;                      // overlays histmat
    u16*   wloT   = whiT + F_IN*D1;
    u16*   w2hiT  = wloT + F_IN*D1;
    u16*   w2loT  = w2hiT + D1*OUT_C;
    u16*   h1b    = (u16*)h1f;
    u16*   h2b    = (u16*)h2f;

    // ---- CSR build (atomic-free counting sort, u16 histmat)
    hipLaunchKernelGGL(k_histB,   dim3(NHB), dim3(HTHREADS), 0, stream, dst_a, E, CE, histmat);
    hipLaunchKernelGGL(k_colscan, dim3(SNBLK), dim3(256), 0, stream, histmat, cnt);
    hipLaunchKernelGGL(k_scanA,   dim3(SNBLK), dim3(256), 0, stream, cnt, bsum);
    hipLaunchKernelGGL(k_scanB,   dim3(1), dim3(256), 0, stream, bsum, boff, rowptr);
    hipLaunchKernelGGL(k_scanC,   dim3(SNBLK), dim3(256), 0, stream, cnt, boff, rowptr);
    hipLaunchKernelGGL(k_scatterB,dim3(NHB), dim3(HTHREADS), 0, stream,
                       src_a, dst_a, E, CE, histmat, rowptr, srcs);

    // ---- weight prep (histmat dead after scatterB)
    hipLaunchKernelGGL(k_cvtW2, dim3((D1*OUT_C+255)/256), dim3(256), 0, stream,
                       W2, w2hiT, w2loT);
    hipLaunchKernelGGL(k_cvtW, dim3((F_IN*D1+255)/256), dim3(256), 0, stream,
                       W1, whiT, wloT);

    // ---- layer 1
    hipLaunchKernelGGL(k_gemm1, dim3((N_NODES+63)/64), dim3(256), 0, stream,
                       x, whiT, wloT, att_src1, att_dst1, h1b, asrc1, adst1);
    hipLaunchKernelGGL(k_agg1, dim3((N_NODES+3)/4), dim3(256), 0, stream,
                       rowptr, srcs, asrc1, adst1, h1b, out1);

    // ---- layer 2
    hipLaunchKernelGGL(k_gemm2, dim3((N_NODES+63)/64), dim3(256), 0, stream,
                       out1, b1, w2hiT, w2loT, att_src2, att_dst2, h2b, asrc2, adst2);
    hipLaunchKernelGGL(k_agg2, dim3((N_NODES+3)/4), dim3(256), 0, stream,
                       rowptr, srcs, asrc2, adst2, h2b, b2, out);
}

// Round 14
// 222.948 us; speedup vs baseline: 1.2314x; 1.2314x over previous
//
#include <hip/hip_runtime.h>
#include <math.h>

#define N_NODES 50000
#define F_IN    512
#define H1      8
#define C1      8
#define D1      64    // H1*C1
#define OUT_C   128
#define NEG     0.2f

#define SCHUNK  256
#define SNBLK   ((N_NODES + SCHUNK - 1)/SCHUNK)   // 196

#define NHB      256    // histogram/scatter blocks
#define HTHREADS 1024
#define HALF     25000  // nodes per LDS pass
#define HWORDS   12500  // packed u32 words per pass (2 u16 counters each)

#define G1_ROWS  256
#define NB1      ((N_NODES + G1_ROWS - 1)/G1_ROWS)   // 196

using bf16x8 = __attribute__((ext_vector_type(8))) short;
using f32x4  = __attribute__((ext_vector_type(4))) float;
typedef unsigned short u16;
typedef unsigned int   u32;

__device__ __forceinline__ float leaky(float x){
    return fmaxf(x, 0.f) + NEG * fminf(x, 0.f);
}
__device__ __forceinline__ u16 f2bf(float f){           // RNE
    u32 u = __float_as_uint(f);
    u32 r = u + 0x7FFF + ((u>>16)&1);
    return (u16)(r>>16);
}
__device__ __forceinline__ float bf2f(u16 h){ return __uint_as_float(((u32)h)<<16); }

// split-convert 8 f32 -> bf16 hi + bf16 residual
__device__ __forceinline__ void cvt8(const float4& a, const float4& b, bf16x8& hi, bf16x8& lo){
    u16 h0=f2bf(a.x),h1=f2bf(a.y),h2=f2bf(a.z),h3=f2bf(a.w);
    u16 h4=f2bf(b.x),h5=f2bf(b.y),h6=f2bf(b.z),h7=f2bf(b.w);
    hi = (bf16x8){(short)h0,(short)h1,(short)h2,(short)h3,
                  (short)h4,(short)h5,(short)h6,(short)h7};
    lo = (bf16x8){(short)f2bf(a.x-bf2f(h0)),(short)f2bf(a.y-bf2f(h1)),
                  (short)f2bf(a.z-bf2f(h2)),(short)f2bf(a.w-bf2f(h3)),
                  (short)f2bf(b.x-bf2f(h4)),(short)f2bf(b.y-bf2f(h5)),
                  (short)f2bf(b.z-bf2f(h6)),(short)f2bf(b.w-bf2f(h7))};
}

// ---------------------------------------------------------------- per-block LDS histogram -> histmat[blk][node] (u16)
__global__ __launch_bounds__(1024) void k_histB(const int* __restrict__ dst_a, int E, int CE,
                                                u16* __restrict__ histmat){
    __shared__ u32 lcnt[HWORDS];
    const int blk = blockIdx.x;
    const int i0 = blk*CE;
    const int i1 = min(i0+CE, E + N_NODES);
    for (int p=0;p<2;p++){
        for (int w=threadIdx.x; w<HWORDS; w+=HTHREADS) lcnt[w]=0;
        __syncthreads();
        const int lo = p*HALF, hi = lo+HALF;
        for (int i=i0+(int)threadIdx.x; i<i1; i+=HTHREADS){
            int d = (i<E)? dst_a[i] : (i-E);
            if (d>=lo && d<hi){
                int dd = d - lo;
                atomicAdd(&lcnt[dd>>1], 1u<<((dd&1)*16));
            }
        }
        __syncthreads();
        u16* dst = histmat + (size_t)blk*N_NODES + lo;
        for (int w=threadIdx.x; w<HWORDS; w+=HTHREADS){
            *(u32*)(dst + 2*w) = lcnt[w];
        }
        __syncthreads();
    }
}

// ---------------------------------------------------------------- column scan: histmat -> per-block exclusive prefix (u16), cnt
__global__ __launch_bounds__(256) void k_colscan(u16* __restrict__ histmat, int* __restrict__ cnt){
    int n = blockIdx.x*256 + threadIdx.x;
    if (n >= N_NODES) return;
    u32 run = 0;
    u16* p = histmat + n;
    #pragma unroll 4
    for (int b=0;b<NHB;b++){
        u32 v = p[(size_t)b*N_NODES];
        p[(size_t)b*N_NODES] = (u16)run;
        run += v;
    }
    cnt[n] = (int)run;
}

// ---------------------------------------------------------------- 3-phase scan over cnt -> rowptr
__global__ __launch_bounds__(256) void k_scanA(const int* __restrict__ cnt, int* bsum){
    __shared__ int sm[256];
    int idx = blockIdx.x*256 + threadIdx.x;
    int v = (idx < N_NODES) ? cnt[idx] : 0;
    sm[threadIdx.x] = v; __syncthreads();
    for (int off=128; off>0; off>>=1){
        if (threadIdx.x < off) sm[threadIdx.x] += sm[threadIdx.x+off];
        __syncthreads();
    }
    if (threadIdx.x==0) bsum[blockIdx.x] = sm[0];
}

__global__ __launch_bounds__(256) void k_scanB(const int* __restrict__ bsum, int* boff, int* rowptr){
    __shared__ int sm[256];
    int t = threadIdx.x;
    int v = (t < SNBLK) ? bsum[t] : 0;
    sm[t]=v; __syncthreads();
    for (int off=1; off<256; off<<=1){
        int u = (t>=off)? sm[t-off] : 0;
        __syncthreads();
        sm[t]+=u; __syncthreads();
    }
    if (t < SNBLK) boff[t] = sm[t] - v;       // exclusive
    if (t==255) rowptr[N_NODES] = sm[255];    // total = E + N
}

__global__ __launch_bounds__(256) void k_scanC(const int* __restrict__ cnt, const int* __restrict__ boff,
                                               int* rowptr){
    __shared__ int sm[256];
    int idx = blockIdx.x*256 + threadIdx.x;
    int t = threadIdx.x;
    int v = (idx<N_NODES)? cnt[idx] : 0;
    sm[t]=v; __syncthreads();
    for (int off=1; off<256; off<<=1){
        int u = (t>=off)? sm[t-off] : 0;
        __syncthreads();
        sm[t]+=u; __syncthreads();
    }
    if (idx<N_NODES){
        rowptr[idx] = boff[blockIdx.x] + sm[t] - v;
    }
}

// ---------------------------------------------------------------- atomic-free scatter (LDS local ranks)
__global__ __launch_bounds__(1024) void k_scatterB(const int* __restrict__ src_a, const int* __restrict__ dst_a,
                                                   int E, int CE,
                                                   const u16* __restrict__ histmat, const int* __restrict__ rowptr,
                                                   int* __restrict__ srcs){
    __shared__ u32 lcnt[HWORDS];
    const int blk = blockIdx.x;
    const int i0 = blk*CE;
    const int i1 = min(i0+CE, E + N_NODES);
    const u16* __restrict__ pb = histmat + (size_t)blk*N_NODES;
    for (int p=0;p<2;p++){
        for (int w=threadIdx.x; w<HWORDS; w+=HTHREADS) lcnt[w]=0;
        __syncthreads();
        const int lo = p*HALF, hi = lo+HALF;
        for (int i=i0+(int)threadIdx.x; i<i1; i+=HTHREADS){
            int s, d;
            if (i<E){ s=src_a[i]; d=dst_a[i]; } else { s=d=i-E; }
            if (d>=lo && d<hi){
                int dd = d - lo;
                u32 old = atomicAdd(&lcnt[dd>>1], 1u<<((dd&1)*16));
                u32 rank = (old >> ((dd&1)*16)) & 0xFFFFu;
                int pos = rowptr[d] + (int)pb[d] + (int)rank;
                srcs[pos] = s;
            }
        }
        __syncthreads();
    }
}

// ---------------------------------------------------------------- W1 split/transpose: whiT/wloT [64 col][512 k] bf16
__global__ void k_cvtW(const float* __restrict__ W1, u16* __restrict__ whiT, u16* __restrict__ wloT){
    int i = blockIdx.x*blockDim.x + threadIdx.x;   // 0..32767
    if (i >= F_IN*D1) return;
    int k = i >> 6, col = i & 63;
    float v = W1[i];
    u16 hi = f2bf(v);
    float lo = v - bf2f(hi);
    whiT[col*F_IN + k] = hi;
    wloT[col*F_IN + k] = f2bf(lo);
}

// ---------------------------------------------------------------- W2 split/transpose: [128 col][64 k] bf16
__global__ void k_cvtW2(const float* __restrict__ W2, u16* __restrict__ w2hiT, u16* __restrict__ w2loT){
    int i = blockIdx.x*blockDim.x + threadIdx.x;   // 0..8191
    if (i >= D1*OUT_C) return;
    int k = i >> 7, col = i & 127;
    float v = W2[i];
    u16 hi = f2bf(v);
    float lo = v - bf2f(hi);
    w2hiT[col*D1 + k] = hi;
    w2loT[col*D1 + k] = f2bf(lo);
}

// ---------------------------------------------------------------- GEMM1 via MFMA: B (hi+lo) resident in LDS, A direct+prefetch
// block: 1024 thr = 16 waves; each wave 16 rows x 64 cols; 256 rows/block
__global__ __launch_bounds__(1024) void k_gemm1(
        const float* __restrict__ x,
        const u16* __restrict__ whiT, const u16* __restrict__ wloT,
        const float* __restrict__ att_src, const float* __restrict__ att_dst,
        u16* __restrict__ h1b, float* __restrict__ asrc, float* __restrict__ adst){
    __shared__ u16 Bh[D1*F_IN];   // 64 KB, XOR-swizzled [col][k]
    __shared__ u16 Bl[D1*F_IN];   // 64 KB
    const int tid = threadIdx.x;
    const int wid = tid>>6, l = tid&63;
    const int lq = l>>4, lr = l&15;

    // stage B: coalesced reads, swizzled LDS writes (conflict-free: 64 chunks/row)
    for (int i = tid; i < (D1*F_IN)/8; i += 1024){
        int col = i >> 6;                      // 64 x 16B chunks per col-row
        int c   = i & 63;
        int boff = (col*1024 + c*16) ^ ((col&7)<<4);
        *(uint4*)((char*)Bh + boff) = *(const uint4*)(whiT + (size_t)i*8);
        *(uint4*)((char*)Bl + boff) = *(const uint4*)(wloT + (size_t)i*8);
    }
    __syncthreads();

    const int wavebase = blockIdx.x*G1_ROWS + wid*16;
    const int arow = min(wavebase + lr, N_NODES-1);
    const float* __restrict__ xrow = x + (size_t)arow*F_IN + lq*8;

    f32x4 acc[4];
    #pragma unroll
    for (int n=0;n<4;n++) acc[n] = (f32x4){0.f,0.f,0.f,0.f};

    // prefetch K-step 0 (two kt segments of 32B each)
    float4 p0 = *(const float4*)(xrow);
    float4 p1 = *(const float4*)(xrow+4);
    float4 p2 = *(const float4*)(xrow+32);
    float4 p3 = *(const float4*)(xrow+36);

    for (int ks=0; ks<8; ks++){
        bf16x8 ahi0, alo0, ahi1, alo1;
        cvt8(p0, p1, ahi0, alo0);
        cvt8(p2, p3, ahi1, alo1);
        if (ks < 7){
            const float* nx = xrow + (ks+1)*64;
            p0 = *(const float4*)(nx);
            p1 = *(const float4*)(nx+4);
            p2 = *(const float4*)(nx+32);
            p3 = *(const float4*)(nx+36);
        }
        const int k0 = ks*64;
        #pragma unroll
        for (int n=0;n<4;n++){
            const int colb = n*16 + lr;
            const int swz  = (colb&7)<<4;
            const int b0 = (colb*1024 + (k0 + lq*8)*2) ^ swz;
            const int b1 = (colb*1024 + (k0 + 32 + lq*8)*2) ^ swz;
            bf16x8 bhi0 = *(const bf16x8*)((const char*)Bh + b0);
            bf16x8 blo0 = *(const bf16x8*)((const char*)Bl + b0);
            acc[n] = __builtin_amdgcn_mfma_f32_16x16x32_bf16(ahi0, bhi0, acc[n], 0,0,0);
            acc[n] = __builtin_amdgcn_mfma_f32_16x16x32_bf16(ahi0, blo0, acc[n], 0,0,0);
            acc[n] = __builtin_amdgcn_mfma_f32_16x16x32_bf16(alo0, bhi0, acc[n], 0,0,0);
            bf16x8 bhi1 = *(const bf16x8*)((const char*)Bh + b1);
            bf16x8 blo1 = *(const bf16x8*)((const char*)Bl + b1);
            acc[n] = __builtin_amdgcn_mfma_f32_16x16x32_bf16(ahi1, bhi1, acc[n], 0,0,0);
            acc[n] = __builtin_amdgcn_mfma_f32_16x16x32_bf16(ahi1, blo1, acc[n], 0,0,0);
            acc[n] = __builtin_amdgcn_mfma_f32_16x16x32_bf16(alo1, bhi1, acc[n], 0,0,0);
        }
    }

    // epilogue: C/D layout col=lane&15, row=(lane>>4)*4+i  [HW-verified]
    #pragma unroll
    for (int n=0;n<4;n++){
        int col = n*16 + lr;
        float as_w = att_src[col], ad_w = att_dst[col];
        #pragma unroll
        for (int i=0;i<4;i++){
            int node = wavebase + lq*4 + i;
            float v = acc[n][i];
            float s = v*as_w, d = v*ad_w;
            s += __shfl_xor(s,1); d += __shfl_xor(d,1);
            s += __shfl_xor(s,2); d += __shfl_xor(d,2);
            s += __shfl_xor(s,4); d += __shfl_xor(d,4);
            if (node < N_NODES){
                h1b[(size_t)node*D1 + col] = f2bf(v);
                if ((l&7)==0){
                    int head = col>>3;
                    asrc[node*H1 + head] = s;
                    adst[node*H1 + head] = d;
                }
            }
        }
    }
}

// ---------------------------------------------------------------- layer1 aggregation: 8 edges per gather instruction
__global__ __launch_bounds__(256) void k_agg1(
        const int* __restrict__ rowptr, const int* __restrict__ srcs,
        const float* __restrict__ asrc1, const float* __restrict__ adst1,
        const u16* __restrict__ h1b, float* __restrict__ out1){
    const int node = blockIdx.x*4 + (threadIdx.x>>6);
    const int lane = threadIdx.x & 63;
    const int g = lane >> 3;
    const int p = lane & 7;
    const int r0 = __builtin_amdgcn_readfirstlane(rowptr[node]);
    const int r1 = __builtin_amdgcn_readfirstlane(rowptr[node+1]);
    const float ad = adst1[node*H1 + p];
    float a0=0,a1=0,a2=0,a3=0,a4=0,a5=0,a6=0,a7=0, den=0;
    for (int base=r0; base<r1; base+=64){
        int eidx = base + lane;
        int sl = srcs[eidx < r1 ? eidx : (r1-1)];
        const int m = min(64, r1-base);
        for (int k=0; k*8 < m; k++){
            int e = k*8 + g;
            int s = __shfl(sl, e);
            float w = (base + e < r1) ? __expf(leaky(asrc1[s*H1 + p] + ad)) : 0.f;
            uint4 pv = *(const uint4*)(h1b + (size_t)s*D1 + p*8);
            a0 += w*bf2f((u16)(pv.x&0xFFFFu)); a1 += w*bf2f((u16)(pv.x>>16));
            a2 += w*bf2f((u16)(pv.y&0xFFFFu)); a3 += w*bf2f((u16)(pv.y>>16));
            a4 += w*bf2f((u16)(pv.z&0xFFFFu)); a5 += w*bf2f((u16)(pv.z>>16));
            a6 += w*bf2f((u16)(pv.w&0xFFFFu)); a7 += w*bf2f((u16)(pv.w>>16));
            den += w;
        }
    }
    #pragma unroll
    for (int off=8; off<64; off<<=1){
        a0 += __shfl_xor(a0,off); a1 += __shfl_xor(a1,off);
        a2 += __shfl_xor(a2,off); a3 += __shfl_xor(a3,off);
        a4 += __shfl_xor(a4,off); a5 += __shfl_xor(a5,off);
        a6 += __shfl_xor(a6,off); a7 += __shfl_xor(a7,off);
        den += __shfl_xor(den,off);
    }
    if (g == 0){
        float inv = 1.f/den;
        float* o = out1 + (size_t)node*D1 + p*8;
        *(float4*)(o)   = make_float4(a0*inv, a1*inv, a2*inv, a3*inv);
        *(float4*)(o+4) = make_float4(a4*inv, a5*inv, a6*inv, a7*inv);
    }
}

// ---------------------------------------------------------------- GEMM2 via MFMA: h2 = elu(out1+b1) @ W2 (+alpha epilogue); h2 stored bf16
__global__ __launch_bounds__(256) void k_gemm2(
        const float* __restrict__ out1, const float* __restrict__ b1,
        const u16* __restrict__ w2hiT, const u16* __restrict__ w2loT,
        const float* __restrict__ att_src2, const float* __restrict__ att_dst2,
        u16* __restrict__ h2b, float* __restrict__ asrc2, float* __restrict__ adst2){
    __shared__ u16 Ahi[64*64];   // 8 KB, XOR-swizzled
    __shared__ u16 Alo[64*64];   // 8 KB
    const int tid = threadIdx.x;
    const int wid = tid>>6, l = tid&63;
    const int lq = l>>4, lr = l&15;
    const int rowbase = blockIdx.x*64;

    #pragma unroll
    for (int q=0;q<4;q++){
        int p = tid + 256*q;
        int r = p>>4, kseg = p&15;
        int grow = min(rowbase + r, N_NODES-1);
        float4 v = *(const float4*)(out1 + (size_t)grow*D1 + kseg*4);
        float4 bb = *(const float4*)(b1 + kseg*4);
        float a0 = v.x+bb.x, a1 = v.y+bb.y, a2 = v.z+bb.z, a3 = v.w+bb.w;
        a0 = a0>0.f ? a0 : (__expf(a0)-1.f);
        a1 = a1>0.f ? a1 : (__expf(a1)-1.f);
        a2 = a2>0.f ? a2 : (__expf(a2)-1.f);
        a3 = a3>0.f ? a3 : (__expf(a3)-1.f);
        u16 h0=f2bf(a0), h1v=f2bf(a1), h2v=f2bf(a2), h3v=f2bf(a3);
        u16 e0=f2bf(a0-bf2f(h0)), e1=f2bf(a1-bf2f(h1v)),
            e2=f2bf(a2-bf2f(h2v)), e3=f2bf(a3-bf2f(h3v));
        int boff = (r*128 + kseg*8) ^ ((r&7)<<4);
        *(ushort4*)((char*)Ahi + boff) = make_ushort4(h0,h1v,h2v,h3v);
        *(ushort4*)((char*)Alo + boff) = make_ushort4(e0,e1,e2,e3);
    }
    __syncthreads();

    const int arow = wid*16 + lr;
    bf16x8 ahi[2], alo[2];
    #pragma unroll
    for (int kt=0;kt<2;kt++){
        int boff = (arow*128 + kt*64 + lq*16) ^ ((arow&7)<<4);
        ahi[kt] = *(const bf16x8*)((const char*)Ahi + boff);
        alo[kt] = *(const bf16x8*)((const char*)Alo + boff);
    }

    f32x4 acc[8];
    #pragma unroll
    for (int n=0;n<8;n++) acc[n] = (f32x4){0.f,0.f,0.f,0.f};
    #pragma unroll
    for (int n=0;n<8;n++){
        #pragma unroll
        for (int kt=0;kt<2;kt++){
            const size_t wo = (size_t)(n*16+lr)*D1 + kt*32 + lq*8;
            bf16x8 bhi = *(const bf16x8*)(w2hiT + wo);
            bf16x8 blo = *(const bf16x8*)(w2loT + wo);
            acc[n] = __builtin_amdgcn_mfma_f32_16x16x32_bf16(ahi[kt], bhi, acc[n], 0,0,0);
            acc[n] = __builtin_amdgcn_mfma_f32_16x16x32_bf16(ahi[kt], blo, acc[n], 0,0,0);
            acc[n] = __builtin_amdgcn_mfma_f32_16x16x32_bf16(alo[kt], bhi, acc[n], 0,0,0);
        }
    }

    float aw[8], dw[8];
    #pragma unroll
    for (int n=0;n<8;n++){ aw[n]=att_src2[n*16+lr]; dw[n]=att_dst2[n*16+lr]; }
    #pragma unroll
    for (int i=0;i<4;i++){
        int node = rowbase + wid*16 + lq*4 + i;
        bool ok = node < N_NODES;
        float s = 0.f, d = 0.f;
        #pragma unroll
        for (int n=0;n<8;n++){
            float v = acc[n][i];
            s = fmaf(v, aw[n], s);
            d = fmaf(v, dw[n], d);
            if (ok) h2b[(size_t)node*OUT_C + n*16 + lr] = f2bf(v);
        }
        s += __shfl_xor(s,1); d += __shfl_xor(d,1);
        s += __shfl_xor(s,2); d += __shfl_xor(d,2);
        s += __shfl_xor(s,4); d += __shfl_xor(d,4);
        s += __shfl_xor(s,8); d += __shfl_xor(d,8);
        if (ok && lr==0){ asrc2[node]=s; adst2[node]=d; }
    }
}

// ---------------------------------------------------------------- layer2 aggregation: 4 edges per gather instruction
__global__ __launch_bounds__(256) void k_agg2(
        const int* __restrict__ rowptr, const int* __restrict__ srcs,
        const float* __restrict__ asrc2, const float* __restrict__ adst2,
        const u16* __restrict__ h2b, const float* __restrict__ b2,
        float* __restrict__ out){
    const int node = blockIdx.x*4 + (threadIdx.x>>6);
    const int lane = threadIdx.x & 63;
    const int g = lane >> 4;
    const int p = lane & 15;
    const int r0 = __builtin_amdgcn_readfirstlane(rowptr[node]);
    const int r1 = __builtin_amdgcn_readfirstlane(rowptr[node+1]);
    const float ad = adst2[node];
    float a0=0,a1=0,a2=0,a3=0,a4=0,a5=0,a6=0,a7=0, den=0;
    for (int base=r0; base<r1; base+=64){
        int eidx = base + lane;
        int sl = srcs[eidx < r1 ? eidx : (r1-1)];
        float wl = (eidx < r1) ? __expf(leaky(asrc2[sl] + ad)) : 0.f;
        const int m = min(64, r1-base);
        for (int k=0; k*4 < m; k++){
            int e = k*4 + g;
            int   s = __shfl(sl, e);
            float w = __shfl(wl, e);      // 0 for padded slots
            uint4 pv = *(const uint4*)(h2b + (size_t)s*OUT_C + p*8);
            a0 += w*bf2f((u16)(pv.x&0xFFFFu)); a1 += w*bf2f((u16)(pv.x>>16));
            a2 += w*bf2f((u16)(pv.y&0xFFFFu)); a3 += w*bf2f((u16)(pv.y>>16));
            a4 += w*bf2f((u16)(pv.z&0xFFFFu)); a5 += w*bf2f((u16)(pv.z>>16));
            a6 += w*bf2f((u16)(pv.w&0xFFFFu)); a7 += w*bf2f((u16)(pv.w>>16));
            den += w;
        }
    }
    #pragma unroll
    for (int off=16; off<64; off<<=1){
        a0 += __shfl_xor(a0,off); a1 += __shfl_xor(a1,off);
        a2 += __shfl_xor(a2,off); a3 += __shfl_xor(a3,off);
        a4 += __shfl_xor(a4,off); a5 += __shfl_xor(a5,off);
        a6 += __shfl_xor(a6,off); a7 += __shfl_xor(a7,off);
        den += __shfl_xor(den,off);
    }
    if (g == 0){
        float inv = 1.f/den;
        const float* bb = b2 + p*8;
        float* o = out + (size_t)node*OUT_C + p*8;
        *(float4*)(o)   = make_float4(a0*inv+bb[0], a1*inv+bb[1], a2*inv+bb[2], a3*inv+bb[3]);
        *(float4*)(o+4) = make_float4(a4*inv+bb[4], a5*inv+bb[5], a6*inv+bb[6], a7*inv+bb[7]);
    }
}

// ---------------------------------------------------------------- launch
extern "C" void kernel_launch(void* const* d_in, const int* in_sizes, int n_in,
                              void* d_out, int out_size, void* d_ws, size_t ws_size,
                              hipStream_t stream) {
    const float* x        = (const float*)d_in[0];
    const int*   edge     = (const int*)  d_in[1];
    const float* W1       = (const float*)d_in[2];
    const float* att_src1 = (const float*)d_in[3];
    const float* att_dst1 = (const float*)d_in[4];
    const float* b1       = (const float*)d_in[5];
    const float* W2       = (const float*)d_in[6];
    const float* att_src2 = (const float*)d_in[7];
    const float* att_dst2 = (const float*)d_in[8];
    const float* b2       = (const float*)d_in[9];
    float* out = (float*)d_out;

    const int E  = in_sizes[1] / 2;
    const int ET = E + N_NODES;
    const int CE = (ET + NHB - 1) / NHB;
    const int* src_a = edge;
    const int* dst_a = edge + E;

    // workspace layout (element counts sized for f32 regions; h1/h2 use half as u16)
    float* ws = (float*)d_ws;
    float* h1f   = ws;                            // N*64 f32 region -> used as u16 h1b
    float* asrc1 = h1f   + (size_t)N_NODES*D1;    // N*8
    float* adst1 = asrc1 + (size_t)N_NODES*H1;    // N*8
    float* out1  = adst1 + (size_t)N_NODES*H1;    // N*64
    float* h2f   = out1  + (size_t)N_NODES*D1;    // N*128 f32 region -> used as u16 h2b
    float* asrc2 = h2f   + (size_t)N_NODES*OUT_C; // N
    float* adst2 = asrc2 + N_NODES;               // N
    int*   cnt    = (int*)(adst2 + N_NODES);      // N
    int*   rowptr = cnt    + N_NODES;             // N+4
    int*   srcs   = rowptr + (N_NODES+4);         // ET
    int*   bsum   = srcs   + ET;                  // 256
    int*   boff   = bsum   + 256;                 // 256
    u16*   histmat= (u16*)(boff + 256);           // NHB*N u16 (25.6 MB; dead after scatterB)
    u16*   whiT   = histmat;                      // overlays histmat
    u16*   wloT   = whiT + F_IN*D1;
    u16*   w2hiT  = wloT + F_IN*D1;
    u16*   w2loT  = w2hiT + D1*OUT_C;
    u16*   h1b    = (u16*)h1f;
    u16*   h2b    = (u16*)h2f;

    // ---- CSR build (atomic-free counting sort, u16 histmat)
    hipLaunchKernelGGL(k_histB,   dim3(NHB), dim3(HTHREADS), 0, stream, dst_a, E, CE, histmat);
    hipLaunchKernelGGL(k_colscan, dim3(SNBLK), dim3(256), 0, stream, histmat, cnt);
    hipLaunchKernelGGL(k_scanA,   dim3(SNBLK), dim3(256), 0, stream, cnt, bsum);
    hipLaunchKernelGGL(k_scanB,   dim3(1), dim3(256), 0, stream, bsum, boff, rowptr);
    hipLaunchKernelGGL(k_scanC,   dim3(SNBLK), dim3(256), 0, stream, cnt, boff, rowptr);
    hipLaunchKernelGGL(k_scatterB,dim3(NHB), dim3(HTHREADS), 0, stream,
                       src_a, dst_a, E, CE, histmat, rowptr, srcs);

    // ---- weight prep (histmat dead after scatterB)
    hipLaunchKernelGGL(k_cvtW2, dim3((D1*OUT_C+255)/256), dim3(256), 0, stream,
                       W2, w2hiT, w2loT);
    hipLaunchKernelGGL(k_cvtW, dim3((F_IN*D1+255)/256), dim3(256), 0, stream,
                       W1, whiT, wloT);

    // ---- layer 1
    hipLaunchKernelGGL(k_gemm1, dim3(NB1), dim3(1024), 0, stream,
                       x, whiT, wloT, att_src1, att_dst1, h1b, asrc1, adst1);
    hipLaunchKernelGGL(k_agg1, dim3((N_NODES+3)/4), dim3(256), 0, stream,
                       rowptr, srcs, asrc1, adst1, h1b, out1);

    // ---- layer 2
    hipLaunchKernelGGL(k_gemm2, dim3((N_NODES+63)/64), dim3(256), 0, stream,
                       out1, b1, w2hiT, w2loT, att_src2, att_dst2, h2b, asrc2, adst2);
    hipLaunchKernelGGL(k_agg2, dim3((N_NODES+3)/4), dim3(256), 0, stream,
                       rowptr, srcs, asrc2, adst2, h2b, b2, out);
}

// Round 15
// 212.997 us; speedup vs baseline: 1.2889x; 1.0467x over previous
//
#include <hip/hip_runtime.h>
#include <math.h>

#define N_NODES 50000
#define F_IN    512
#define H1      8
#define C1      8
#define D1      64    // H1*C1
#define OUT_C   128
#define NEG     0.2f

#define SCHUNK  256
#define SNBLK   ((N_NODES + SCHUNK - 1)/SCHUNK)   // 196

#define NHB      256    // histogram/scatter blocks
#define HTHREADS 1024
#define HW8      ((N_NODES + 3)/4)   // 12500 u32 words of 4x u8 counters

#define G1_ROWS  224
#define G1_THR   896                 // 14 waves
#define NB1      ((N_NODES + G1_ROWS - 1)/G1_ROWS)   // 224

using bf16x8 = __attribute__((ext_vector_type(8))) short;
using f32x4  = __attribute__((ext_vector_type(4))) float;
typedef unsigned short u16;
typedef unsigned int   u32;
typedef unsigned char  u8;

__device__ __forceinline__ float leaky(float x){
    return fmaxf(x, 0.f) + NEG * fminf(x, 0.f);
}
__device__ __forceinline__ u16 f2bf(float f){           // RNE
    u32 u = __float_as_uint(f);
    u32 r = u + 0x7FFF + ((u>>16)&1);
    return (u16)(r>>16);
}
__device__ __forceinline__ float bf2f(u16 h){ return __uint_as_float(((u32)h)<<16); }

// split-convert 8 f32 -> bf16 hi + bf16 residual
__device__ __forceinline__ void cvt8(const float4& a, const float4& b, bf16x8& hi, bf16x8& lo){
    u16 h0=f2bf(a.x),h1=f2bf(a.y),h2=f2bf(a.z),h3=f2bf(a.w);
    u16 h4=f2bf(b.x),h5=f2bf(b.y),h6=f2bf(b.z),h7=f2bf(b.w);
    hi = (bf16x8){(short)h0,(short)h1,(short)h2,(short)h3,
                  (short)h4,(short)h5,(short)h6,(short)h7};
    lo = (bf16x8){(short)f2bf(a.x-bf2f(h0)),(short)f2bf(a.y-bf2f(h1)),
                  (short)f2bf(a.z-bf2f(h2)),(short)f2bf(a.w-bf2f(h3)),
                  (short)f2bf(b.x-bf2f(h4)),(short)f2bf(b.y-bf2f(h5)),
                  (short)f2bf(b.z-bf2f(h6)),(short)f2bf(b.w-bf2f(h7))};
}

// ---------------------------------------------------------------- single-pass per-block histogram -> histmat[blk][node] (u8)
__global__ __launch_bounds__(1024) void k_histB(const int* __restrict__ dst_a, int E, int CE,
                                                u8* __restrict__ histmat){
    __shared__ u32 lcnt[HW8];
    const int blk = blockIdx.x;
    const int i0 = blk*CE;
    const int i1 = min(i0+CE, E + N_NODES);
    for (int w=threadIdx.x; w<HW8; w+=HTHREADS) lcnt[w]=0;
    __syncthreads();
    for (int i=i0+(int)threadIdx.x; i<i1; i+=HTHREADS){
        int d = (i<E)? dst_a[i] : (i-E);
        atomicAdd(&lcnt[d>>2], 1u<<((d&3)*8));
    }
    __syncthreads();
    u32* dst = (u32*)(histmat + (size_t)blk*N_NODES);
    for (int w=threadIdx.x; w<HW8; w+=HTHREADS) dst[w] = lcnt[w];
}

// ---------------------------------------------------------------- column scan (u8 prefix) + per-chunk sum (fused scanA)
__global__ __launch_bounds__(256) void k_colscan(u8* __restrict__ histmat, int* __restrict__ cnt,
                                                 int* __restrict__ bsum){
    __shared__ int sm[256];
    int n = blockIdx.x*256 + threadIdx.x;
    u32 run = 0;
    if (n < N_NODES){
        u8* p = histmat + n;
        #pragma unroll 4
        for (int b=0;b<NHB;b++){
            u32 v = p[(size_t)b*N_NODES];
            p[(size_t)b*N_NODES] = (u8)run;
            run += v;
        }
        cnt[n] = (int)run;
    }
    sm[threadIdx.x] = (n < N_NODES) ? (int)run : 0;
    __syncthreads();
    for (int off=128; off>0; off>>=1){
        if (threadIdx.x < off) sm[threadIdx.x] += sm[threadIdx.x+off];
        __syncthreads();
    }
    if (threadIdx.x==0) bsum[blockIdx.x] = sm[0];
}

// ---------------------------------------------------------------- scan of block sums -> block offsets
__global__ __launch_bounds__(256) void k_scanB(const int* __restrict__ bsum, int* boff, int* rowptr){
    __shared__ int sm[256];
    int t = threadIdx.x;
    int v = (t < SNBLK) ? bsum[t] : 0;
    sm[t]=v; __syncthreads();
    for (int off=1; off<256; off<<=1){
        int u = (t>=off)? sm[t-off] : 0;
        __syncthreads();
        sm[t]+=u; __syncthreads();
    }
    if (t < SNBLK) boff[t] = sm[t] - v;       // exclusive
    if (t==255) rowptr[N_NODES] = sm[255];    // total = E + N
}

__global__ __launch_bounds__(256) void k_scanC(const int* __restrict__ cnt, const int* __restrict__ boff,
                                               int* rowptr){
    __shared__ int sm[256];
    int idx = blockIdx.x*256 + threadIdx.x;
    int t = threadIdx.x;
    int v = (idx<N_NODES)? cnt[idx] : 0;
    sm[t]=v; __syncthreads();
    for (int off=1; off<256; off<<=1){
        int u = (t>=off)? sm[t-off] : 0;
        __syncthreads();
        sm[t]+=u; __syncthreads();
    }
    if (idx<N_NODES){
        rowptr[idx] = boff[blockIdx.x] + sm[t] - v;
    }
}

// ---------------------------------------------------------------- single-pass atomic-free scatter (u8 LDS ranks)
__global__ __launch_bounds__(1024) void k_scatterB(const int* __restrict__ src_a, const int* __restrict__ dst_a,
                                                   int E, int CE,
                                                   const u8* __restrict__ histmat, const int* __restrict__ rowptr,
                                                   int* __restrict__ srcs){
    __shared__ u32 lcnt[HW8];
    const int blk = blockIdx.x;
    const int i0 = blk*CE;
    const int i1 = min(i0+CE, E + N_NODES);
    const u8* __restrict__ pb = histmat + (size_t)blk*N_NODES;
    for (int w=threadIdx.x; w<HW8; w+=HTHREADS) lcnt[w]=0;
    __syncthreads();
    for (int i=i0+(int)threadIdx.x; i<i1; i+=HTHREADS){
        int s, d;
        if (i<E){ s=src_a[i]; d=dst_a[i]; } else { s=d=i-E; }
        u32 old = atomicAdd(&lcnt[d>>2], 1u<<((d&3)*8));
        u32 rank = (old >> ((d&3)*8)) & 0xFFu;
        int pos = rowptr[d] + (int)pb[d] + (int)rank;
        srcs[pos] = s;
    }
}

// ---------------------------------------------------------------- fused W1/W2 split/transpose
__global__ void k_cvtW12(const float* __restrict__ W1, const float* __restrict__ W2,
                         u16* __restrict__ whiT, u16* __restrict__ wloT,
                         u16* __restrict__ w2hiT, u16* __restrict__ w2loT){
    int i = blockIdx.x*blockDim.x + threadIdx.x;
    if (i < F_IN*D1){
        int k = i >> 6, col = i & 63;
        float v = W1[i];
        u16 hi = f2bf(v);
        whiT[col*F_IN + k] = hi;
        wloT[col*F_IN + k] = f2bf(v - bf2f(hi));
    }
    if (i < D1*OUT_C){
        int k = i >> 7, col = i & 127;
        float v = W2[i];
        u16 hi = f2bf(v);
        w2hiT[col*D1 + k] = hi;
        w2loT[col*D1 + k] = f2bf(v - bf2f(hi));
    }
}

// ---------------------------------------------------------------- GEMM1 via MFMA: B (hi+lo) resident in LDS, A direct+prefetch
// block: 896 thr = 14 waves; each wave 16 rows x 64 cols; 224 rows/block; 224 blocks
__global__ __launch_bounds__(G1_THR) void k_gemm1(
        const float* __restrict__ x,
        const u16* __restrict__ whiT, const u16* __restrict__ wloT,
        const float* __restrict__ att_src, const float* __restrict__ att_dst,
        u16* __restrict__ h1b, float* __restrict__ asrc, float* __restrict__ adst){
    __shared__ u16 Bh[D1*F_IN];   // 64 KB, XOR-swizzled [col][k]
    __shared__ u16 Bl[D1*F_IN];   // 64 KB
    const int tid = threadIdx.x;
    const int wid = tid>>6, l = tid&63;
    const int lq = l>>4, lr = l&15;

    // stage B: coalesced reads, swizzled LDS writes
    for (int i = tid; i < (D1*F_IN)/8; i += G1_THR){
        int col = i >> 6;
        int c   = i & 63;
        int boff = (col*1024 + c*16) ^ ((col&7)<<4);
        *(uint4*)((char*)Bh + boff) = *(const uint4*)(whiT + (size_t)i*8);
        *(uint4*)((char*)Bl + boff) = *(const uint4*)(wloT + (size_t)i*8);
    }
    __syncthreads();

    const int wavebase = blockIdx.x*G1_ROWS + wid*16;
    const int arow = min(wavebase + lr, N_NODES-1);
    const float* __restrict__ xrow = x + (size_t)arow*F_IN + lq*8;

    f32x4 acc[4];
    #pragma unroll
    for (int n=0;n<4;n++) acc[n] = (f32x4){0.f,0.f,0.f,0.f};

    // prefetch K-step 0
    float4 p0 = *(const float4*)(xrow);
    float4 p1 = *(const float4*)(xrow+4);
    float4 p2 = *(const float4*)(xrow+32);
    float4 p3 = *(const float4*)(xrow+36);

    for (int ks=0; ks<8; ks++){
        bf16x8 ahi0, alo0, ahi1, alo1;
        cvt8(p0, p1, ahi0, alo0);
        cvt8(p2, p3, ahi1, alo1);
        if (ks < 7){
            const float* nx = xrow + (ks+1)*64;
            p0 = *(const float4*)(nx);
            p1 = *(const float4*)(nx+4);
            p2 = *(const float4*)(nx+32);
            p3 = *(const float4*)(nx+36);
        }
        const int k0 = ks*64;
        #pragma unroll
        for (int n=0;n<4;n++){
            const int colb = n*16 + lr;
            const int swz  = (colb&7)<<4;
            const int b0 = (colb*1024 + (k0 + lq*8)*2) ^ swz;
            const int b1 = (colb*1024 + (k0 + 32 + lq*8)*2) ^ swz;
            bf16x8 bhi0 = *(const bf16x8*)((const char*)Bh + b0);
            bf16x8 blo0 = *(const bf16x8*)((const char*)Bl + b0);
            acc[n] = __builtin_amdgcn_mfma_f32_16x16x32_bf16(ahi0, bhi0, acc[n], 0,0,0);
            acc[n] = __builtin_amdgcn_mfma_f32_16x16x32_bf16(ahi0, blo0, acc[n], 0,0,0);
            acc[n] = __builtin_amdgcn_mfma_f32_16x16x32_bf16(alo0, bhi0, acc[n], 0,0,0);
            bf16x8 bhi1 = *(const bf16x8*)((const char*)Bh + b1);
            bf16x8 blo1 = *(const bf16x8*)((const char*)Bl + b1);
            acc[n] = __builtin_amdgcn_mfma_f32_16x16x32_bf16(ahi1, bhi1, acc[n], 0,0,0);
            acc[n] = __builtin_amdgcn_mfma_f32_16x16x32_bf16(ahi1, blo1, acc[n], 0,0,0);
            acc[n] = __builtin_amdgcn_mfma_f32_16x16x32_bf16(alo1, bhi1, acc[n], 0,0,0);
        }
    }

    // epilogue: C/D layout col=lane&15, row=(lane>>4)*4+i  [HW-verified]
    #pragma unroll
    for (int n=0;n<4;n++){
        int col = n*16 + lr;
        float as_w = att_src[col], ad_w = att_dst[col];
        #pragma unroll
        for (int i=0;i<4;i++){
            int node = wavebase + lq*4 + i;
            float v = acc[n][i];
            float s = v*as_w, d = v*ad_w;
            s += __shfl_xor(s,1); d += __shfl_xor(d,1);
            s += __shfl_xor(s,2); d += __shfl_xor(d,2);
            s += __shfl_xor(s,4); d += __shfl_xor(d,4);
            if (node < N_NODES){
                h1b[(size_t)node*D1 + col] = f2bf(v);
                if ((l&7)==0){
                    int head = col>>3;
                    asrc[node*H1 + head] = s;
                    adst[node*H1 + head] = d;
                }
            }
        }
    }
}

// ---------------------------------------------------------------- layer1 aggregation: 8 edges per gather instruction
__global__ __launch_bounds__(256) void k_agg1(
        const int* __restrict__ rowptr, const int* __restrict__ srcs,
        const float* __restrict__ asrc1, const float* __restrict__ adst1,
        const u16* __restrict__ h1b, float* __restrict__ out1){
    const int node = blockIdx.x*4 + (threadIdx.x>>6);
    const int lane = threadIdx.x & 63;
    const int g = lane >> 3;
    const int p = lane & 7;
    const int r0 = __builtin_amdgcn_readfirstlane(rowptr[node]);
    const int r1 = __builtin_amdgcn_readfirstlane(rowptr[node+1]);
    const float ad = adst1[node*H1 + p];
    float a0=0,a1=0,a2=0,a3=0,a4=0,a5=0,a6=0,a7=0, den=0;
    for (int base=r0; base<r1; base+=64){
        int eidx = base + lane;
        int sl = srcs[eidx < r1 ? eidx : (r1-1)];
        const int m = min(64, r1-base);
        for (int k=0; k*8 < m; k++){
            int e = k*8 + g;
            int s = __shfl(sl, e);
            float w = (base + e < r1) ? __expf(leaky(asrc1[s*H1 + p] + ad)) : 0.f;
            uint4 pv = *(const uint4*)(h1b + (size_t)s*D1 + p*8);
            a0 += w*bf2f((u16)(pv.x&0xFFFFu)); a1 += w*bf2f((u16)(pv.x>>16));
            a2 += w*bf2f((u16)(pv.y&0xFFFFu)); a3 += w*bf2f((u16)(pv.y>>16));
            a4 += w*bf2f((u16)(pv.z&0xFFFFu)); a5 += w*bf2f((u16)(pv.z>>16));
            a6 += w*bf2f((u16)(pv.w&0xFFFFu)); a7 += w*bf2f((u16)(pv.w>>16));
            den += w;
        }
    }
    #pragma unroll
    for (int off=8; off<64; off<<=1){
        a0 += __shfl_xor(a0,off); a1 += __shfl_xor(a1,off);
        a2 += __shfl_xor(a2,off); a3 += __shfl_xor(a3,off);
        a4 += __shfl_xor(a4,off); a5 += __shfl_xor(a5,off);
        a6 += __shfl_xor(a6,off); a7 += __shfl_xor(a7,off);
        den += __shfl_xor(den,off);
    }
    if (g == 0){
        float inv = 1.f/den;
        float* o = out1 + (size_t)node*D1 + p*8;
        *(float4*)(o)   = make_float4(a0*inv, a1*inv, a2*inv, a3*inv);
        *(float4*)(o+4) = make_float4(a4*inv, a5*inv, a6*inv, a7*inv);
    }
}

// ---------------------------------------------------------------- GEMM2 via MFMA: h2 = elu(out1+b1) @ W2 (+alpha epilogue); h2 stored bf16
__global__ __launch_bounds__(256) void k_gemm2(
        const float* __restrict__ out1, const float* __restrict__ b1,
        const u16* __restrict__ w2hiT, const u16* __restrict__ w2loT,
        const float* __restrict__ att_src2, const float* __restrict__ att_dst2,
        u16* __restrict__ h2b, float* __restrict__ asrc2, float* __restrict__ adst2){
    __shared__ u16 Ahi[64*64];   // 8 KB, XOR-swizzled
    __shared__ u16 Alo[64*64];   // 8 KB
    const int tid = threadIdx.x;
    const int wid = tid>>6, l = tid&63;
    const int lq = l>>4, lr = l&15;
    const int rowbase = blockIdx.x*64;

    #pragma unroll
    for (int q=0;q<4;q++){
        int p = tid + 256*q;
        int r = p>>4, kseg = p&15;
        int grow = min(rowbase + r, N_NODES-1);
        float4 v = *(const float4*)(out1 + (size_t)grow*D1 + kseg*4);
        float4 bb = *(const float4*)(b1 + kseg*4);
        float a0 = v.x+bb.x, a1 = v.y+bb.y, a2 = v.z+bb.z, a3 = v.w+bb.w;
        a0 = a0>0.f ? a0 : (__expf(a0)-1.f);
        a1 = a1>0.f ? a1 : (__expf(a1)-1.f);
        a2 = a2>0.f ? a2 : (__expf(a2)-1.f);
        a3 = a3>0.f ? a3 : (__expf(a3)-1.f);
        u16 h0=f2bf(a0), h1v=f2bf(a1), h2v=f2bf(a2), h3v=f2bf(a3);
        u16 e0=f2bf(a0-bf2f(h0)), e1=f2bf(a1-bf2f(h1v)),
            e2=f2bf(a2-bf2f(h2v)), e3=f2bf(a3-bf2f(h3v));
        int boff = (r*128 + kseg*8) ^ ((r&7)<<4);
        *(ushort4*)((char*)Ahi + boff) = make_ushort4(h0,h1v,h2v,h3v);
        *(ushort4*)((char*)Alo + boff) = make_ushort4(e0,e1,e2,e3);
    }
    __syncthreads();

    const int arow = wid*16 + lr;
    bf16x8 ahi[2], alo[2];
    #pragma unroll
    for (int kt=0;kt<2;kt++){
        int boff = (arow*128 + kt*64 + lq*16) ^ ((arow&7)<<4);
        ahi[kt] = *(const bf16x8*)((const char*)Ahi + boff);
        alo[kt] = *(const bf16x8*)((const char*)Alo + boff);
    }

    f32x4 acc[8];
    #pragma unroll
    for (int n=0;n<8;n++) acc[n] = (f32x4){0.f,0.f,0.f,0.f};
    #pragma unroll
    for (int n=0;n<8;n++){
        #pragma unroll
        for (int kt=0;kt<2;kt++){
            const size_t wo = (size_t)(n*16+lr)*D1 + kt*32 + lq*8;
            bf16x8 bhi = *(const bf16x8*)(w2hiT + wo);
            bf16x8 blo = *(const bf16x8*)(w2loT + wo);
            acc[n] = __builtin_amdgcn_mfma_f32_16x16x32_bf16(ahi[kt], bhi, acc[n], 0,0,0);
            acc[n] = __builtin_amdgcn_mfma_f32_16x16x32_bf16(ahi[kt], blo, acc[n], 0,0,0);
            acc[n] = __builtin_amdgcn_mfma_f32_16x16x32_bf16(alo[kt], bhi, acc[n], 0,0,0);
        }
    }

    float aw[8], dw[8];
    #pragma unroll
    for (int n=0;n<8;n++){ aw[n]=att_src2[n*16+lr]; dw[n]=att_dst2[n*16+lr]; }
    #pragma unroll
    for (int i=0;i<4;i++){
        int node = rowbase + wid*16 + lq*4 + i;
        bool ok = node < N_NODES;
        float s = 0.f, d = 0.f;
        #pragma unroll
        for (int n=0;n<8;n++){
            float v = acc[n][i];
            s = fmaf(v, aw[n], s);
            d = fmaf(v, dw[n], d);
            if (ok) h2b[(size_t)node*OUT_C + n*16 + lr] = f2bf(v);
        }
        s += __shfl_xor(s,1); d += __shfl_xor(d,1);
        s += __shfl_xor(s,2); d += __shfl_xor(d,2);
        s += __shfl_xor(s,4); d += __shfl_xor(d,4);
        s += __shfl_xor(s,8); d += __shfl_xor(d,8);
        if (ok && lr==0){ asrc2[node]=s; adst2[node]=d; }
    }
}

// ---------------------------------------------------------------- layer2 aggregation: 4 edges per gather instruction
__global__ __launch_bounds__(256) void k_agg2(
        const int* __restrict__ rowptr, const int* __restrict__ srcs,
        const float* __restrict__ asrc2, const float* __restrict__ adst2,
        const u16* __restrict__ h2b, const float* __restrict__ b2,
        float* __restrict__ out){
    const int node = blockIdx.x*4 + (threadIdx.x>>6);
    const int lane = threadIdx.x & 63;
    const int g = lane >> 4;
    const int p = lane & 15;
    const int r0 = __builtin_amdgcn_readfirstlane(rowptr[node]);
    const int r1 = __builtin_amdgcn_readfirstlane(rowptr[node+1]);
    const float ad = adst2[node];
    float a0=0,a1=0,a2=0,a3=0,a4=0,a5=0,a6=0,a7=0, den=0;
    for (int base=r0; base<r1; base+=64){
        int eidx = base + lane;
        int sl = srcs[eidx < r1 ? eidx : (r1-1)];
        float wl = (eidx < r1) ? __expf(leaky(asrc2[sl] + ad)) : 0.f;
        const int m = min(64, r1-base);
        for (int k=0; k*4 < m; k++){
            int e = k*4 + g;
            int   s = __shfl(sl, e);
            float w = __shfl(wl, e);      // 0 for padded slots
            uint4 pv = *(const uint4*)(h2b + (size_t)s*OUT_C + p*8);
            a0 += w*bf2f((u16)(pv.x&0xFFFFu)); a1 += w*bf2f((u16)(pv.x>>16));
            a2 += w*bf2f((u16)(pv.y&0xFFFFu)); a3 += w*bf2f((u16)(pv.y>>16));
            a4 += w*bf2f((u16)(pv.z&0xFFFFu)); a5 += w*bf2f((u16)(pv.z>>16));
            a6 += w*bf2f((u16)(pv.w&0xFFFFu)); a7 += w*bf2f((u16)(pv.w>>16));
            den += w;
        }
    }
    #pragma unroll
    for (int off=16; off<64; off<<=1){
        a0 += __shfl_xor(a0,off); a1 += __shfl_xor(a1,off);
        a2 += __shfl_xor(a2,off); a3 += __shfl_xor(a3,off);
        a4 += __shfl_xor(a4,off); a5 += __shfl_xor(a5,off);
        a6 += __shfl_xor(a6,off); a7 += __shfl_xor(a7,off);
        den += __shfl_xor(den,off);
    }
    if (g == 0){
        float inv = 1.f/den;
        const float* bb = b2 + p*8;
        float* o = out + (size_t)node*OUT_C + p*8;
        *(float4*)(o)   = make_float4(a0*inv+bb[0], a1*inv+bb[1], a2*inv+bb[2], a3*inv+bb[3]);
        *(float4*)(o+4) = make_float4(a4*inv+bb[4], a5*inv+bb[5], a6*inv+bb[6], a7*inv+bb[7]);
    }
}

// ---------------------------------------------------------------- launch
extern "C" void kernel_launch(void* const* d_in, const int* in_sizes, int n_in,
                              void* d_out, int out_size, void* d_ws, size_t ws_size,
                              hipStream_t stream) {
    const float* x        = (const float*)d_in[0];
    const int*   edge     = (const int*)  d_in[1];
    const float* W1       = (const float*)d_in[2];
    const float* att_src1 = (const float*)d_in[3];
    const float* att_dst1 = (const float*)d_in[4];
    const float* b1       = (const float*)d_in[5];
    const float* W2       = (const float*)d_in[6];
    const float* att_src2 = (const float*)d_in[7];
    const float* att_dst2 = (const float*)d_in[8];
    const float* b2       = (const float*)d_in[9];
    float* out = (float*)d_out;

    const int E  = in_sizes[1] / 2;
    const int ET = E + N_NODES;
    const int CE = (ET + NHB - 1) / NHB;
    const int* src_a = edge;
    const int* dst_a = edge + E;

    // workspace layout (element counts sized for f32 regions; h1/h2 use half as u16)
    float* ws = (float*)d_ws;
    float* h1f   = ws;                            // N*64 f32 region -> used as u16 h1b
    float* asrc1 = h1f   + (size_t)N_NODES*D1;    // N*8
    float* adst1 = asrc1 + (size_t)N_NODES*H1;    // N*8
    float* out1  = adst1 + (size_t)N_NODES*H1;    // N*64
    float* h2f   = out1  + (size_t)N_NODES*D1;    // N*128 f32 region -> used as u16 h2b
    float* asrc2 = h2f   + (size_t)N_NODES*OUT_C; // N
    float* adst2 = asrc2 + N_NODES;               // N
    int*   cnt    = (int*)(adst2 + N_NODES);      // N
    int*   rowptr = cnt    + N_NODES;             // N+4
    int*   srcs   = rowptr + (N_NODES+4);         // ET
    int*   bsum   = srcs   + ET;                  // 256
    int*   boff   = bsum   + 256;                 // 256
    u8*    histmat= (u8*)(boff + 256);            // NHB*N u8 (12.8 MB; dead after scatterB)
    u16*   whiT   = (u16*)histmat;                // overlays histmat
    u16*   wloT   = whiT + F_IN*D1;
    u16*   w2hiT  = wloT + F_IN*D1;
    u16*   w2loT  = w2hiT + D1*OUT_C;
    u16*   h1b    = (u16*)h1f;
    u16*   h2b    = (u16*)h2f;

    // ---- CSR build (atomic-free counting sort, u8 histmat, single-pass LDS)
    hipLaunchKernelGGL(k_histB,   dim3(NHB), dim3(HTHREADS), 0, stream, dst_a, E, CE, histmat);
    hipLaunchKernelGGL(k_colscan, dim3(SNBLK), dim3(256), 0, stream, histmat, cnt, bsum);
    hipLaunchKernelGGL(k_scanB,   dim3(1), dim3(256), 0, stream, bsum, boff, rowptr);
    hipLaunchKernelGGL(k_scanC,   dim3(SNBLK), dim3(256), 0, stream, cnt, boff, rowptr);
    hipLaunchKernelGGL(k_scatterB,dim3(NHB), dim3(HTHREADS), 0, stream,
                       src_a, dst_a, E, CE, histmat, rowptr, srcs);

    // ---- weight prep (histmat dead after scatterB)
    hipLaunchKernelGGL(k_cvtW12, dim3((F_IN*D1+255)/256), dim3(256), 0, stream,
                       W1, W2, whiT, wloT, w2hiT, w2loT);

    // ---- layer 1
    hipLaunchKernelGGL(k_gemm1, dim3(NB1), dim3(G1_THR), 0, stream,
                       x, whiT, wloT, att_src1, att_dst1, h1b, asrc1, adst1);
    hipLaunchKernelGGL(k_agg1, dim3((N_NODES+3)/4), dim3(256), 0, stream,
                       rowptr, srcs, asrc1, adst1, h1b, out1);

    // ---- layer 2
    hipLaunchKernelGGL(k_gemm2, dim3((N_NODES+63)/64), dim3(256), 0, stream,
                       out1, b1, w2hiT, w2loT, att_src2, att_dst2, h2b, asrc2, adst2);
    hipLaunchKernelGGL(k_agg2, dim3((N_NODES+3)/4), dim3(256), 0, stream,
                       rowptr, srcs, asrc2, adst2, h2b, b2, out);
}

// Round 16
// 207.428 us; speedup vs baseline: 1.3235x; 1.0269x over previous
//
#include <hip/hip_runtime.h>
#include <math.h>

#define N_NODES 50000
#define F_IN    512
#define H1      8
#define C1      8
#define D1      64    // H1*C1
#define OUT_C   128
#define NEG     0.2f

#define SCHUNK  256
#define SNBLK   ((N_NODES + SCHUNK - 1)/SCHUNK)   // 196

#define NHB      256    // histogram/scatter blocks
#define HTHREADS 1024
#define HW8      ((N_NODES + 3)/4)   // 12500 u32 words of 4x u8 counters

#define G1_ROWS  224
#define G1_THR   896                 // 14 waves
#define NB1      ((N_NODES + G1_ROWS - 1)/G1_ROWS)   // 224

using bf16x8 = __attribute__((ext_vector_type(8))) short;
using f32x4  = __attribute__((ext_vector_type(4))) float;
typedef unsigned short u16;
typedef unsigned int   u32;
typedef unsigned char  u8;

__device__ __forceinline__ float leaky(float x){
    return fmaxf(x, 0.f) + NEG * fminf(x, 0.f);
}
__device__ __forceinline__ u16 f2bf(float f){           // RNE
    u32 u = __float_as_uint(f);
    u32 r = u + 0x7FFF + ((u>>16)&1);
    return (u16)(r>>16);
}
__device__ __forceinline__ float bf2f(u16 h){ return __uint_as_float(((u32)h)<<16); }

// split-convert 8 f32 -> bf16 hi + bf16 residual
__device__ __forceinline__ void cvt8(const float4& a, const float4& b, bf16x8& hi, bf16x8& lo){
    u16 h0=f2bf(a.x),h1=f2bf(a.y),h2=f2bf(a.z),h3=f2bf(a.w);
    u16 h4=f2bf(b.x),h5=f2bf(b.y),h6=f2bf(b.z),h7=f2bf(b.w);
    hi = (bf16x8){(short)h0,(short)h1,(short)h2,(short)h3,
                  (short)h4,(short)h5,(short)h6,(short)h7};
    lo = (bf16x8){(short)f2bf(a.x-bf2f(h0)),(short)f2bf(a.y-bf2f(h1)),
                  (short)f2bf(a.z-bf2f(h2)),(short)f2bf(a.w-bf2f(h3)),
                  (short)f2bf(b.x-bf2f(h4)),(short)f2bf(b.y-bf2f(h5)),
                  (short)f2bf(b.z-bf2f(h6)),(short)f2bf(b.w-bf2f(h7))};
}

// ---------------------------------------------------------------- single-pass per-block histogram -> histmat[blk][node] (u8)
__global__ __launch_bounds__(1024) void k_histB(const int* __restrict__ dst_a, int E, int CE,
                                                u8* __restrict__ histmat){
    __shared__ u32 lcnt[HW8];
    const int blk = blockIdx.x;
    const int i0 = blk*CE;
    const int i1 = min(i0+CE, E + N_NODES);
    for (int w=threadIdx.x; w<HW8; w+=HTHREADS) lcnt[w]=0;
    __syncthreads();
    for (int i=i0+(int)threadIdx.x; i<i1; i+=HTHREADS){
        int d = (i<E)? dst_a[i] : (i-E);
        atomicAdd(&lcnt[d>>2], 1u<<((d&3)*8));
    }
    __syncthreads();
    u32* dst = (u32*)(histmat + (size_t)blk*N_NODES);
    for (int w=threadIdx.x; w<HW8; w+=HTHREADS) dst[w] = lcnt[w];
}

// ---------------------------------------------------------------- column scan (u8 prefix) + per-chunk sum
__global__ __launch_bounds__(256) void k_colscan(u8* __restrict__ histmat, int* __restrict__ cnt,
                                                 int* __restrict__ bsum){
    __shared__ int sm[256];
    int n = blockIdx.x*256 + threadIdx.x;
    u32 run = 0;
    if (n < N_NODES){
        u8* p = histmat + n;
        #pragma unroll 4
        for (int b=0;b<NHB;b++){
            u32 v = p[(size_t)b*N_NODES];
            p[(size_t)b*N_NODES] = (u8)run;
            run += v;
        }
        cnt[n] = (int)run;
    }
    sm[threadIdx.x] = (n < N_NODES) ? (int)run : 0;
    __syncthreads();
    for (int off=128; off>0; off>>=1){
        if (threadIdx.x < off) sm[threadIdx.x] += sm[threadIdx.x+off];
        __syncthreads();
    }
    if (threadIdx.x==0) bsum[blockIdx.x] = sm[0];
}

// ---------------------------------------------------------------- scanC2: per-block bsum prefix + node prefix -> rowptr, fused W cvt
__global__ __launch_bounds__(256) void k_scanC2(const int* __restrict__ cnt, const int* __restrict__ bsum,
                                                int* __restrict__ rowptr,
                                                const float* __restrict__ W1, const float* __restrict__ W2,
                                                u16* __restrict__ whiT, u16* __restrict__ wloT,
                                                u16* __restrict__ w2hiT, u16* __restrict__ w2loT){
    __shared__ int sm[256];
    __shared__ int base;
    const int t = threadIdx.x;
    // redundant per-block prefix over bsum (196 entries)
    int v = (t < SNBLK) ? bsum[t] : 0;
    sm[t] = v; __syncthreads();
    for (int off=1; off<256; off<<=1){
        int u = (t>=off)? sm[t-off] : 0;
        __syncthreads();
        sm[t]+=u; __syncthreads();
    }
    if (t==0) base = (blockIdx.x==0) ? 0 : sm[blockIdx.x-1];
    if (blockIdx.x==0 && t==255) rowptr[N_NODES] = sm[SNBLK-1];
    __syncthreads();
    const int myoff = base;
    // per-node exclusive prefix within chunk
    int idx = blockIdx.x*256 + t;
    int c = (idx<N_NODES)? cnt[idx] : 0;
    __syncthreads();
    sm[t]=c; __syncthreads();
    for (int off=1; off<256; off<<=1){
        int u = (t>=off)? sm[t-off] : 0;
        __syncthreads();
        sm[t]+=u; __syncthreads();
    }
    if (idx<N_NODES) rowptr[idx] = myoff + sm[t] - c;
    // fused weight split/transpose (50176 threads cover 32768)
    int gid = blockIdx.x*256 + t;
    if (gid < F_IN*D1){
        int k = gid >> 6, col = gid & 63;
        float w = W1[gid];
        u16 hi = f2bf(w);
        whiT[col*F_IN + k] = hi;
        wloT[col*F_IN + k] = f2bf(w - bf2f(hi));
    }
    if (gid < D1*OUT_C){
        int k = gid >> 7, col = gid & 127;
        float w = W2[gid];
        u16 hi = f2bf(w);
        w2hiT[col*D1 + k] = hi;
        w2loT[col*D1 + k] = f2bf(w - bf2f(hi));
    }
}

// ---------------------------------------------------------------- single-pass atomic-free scatter (u8 LDS ranks, u16 srcs)
__global__ __launch_bounds__(1024) void k_scatterB(const int* __restrict__ src_a, const int* __restrict__ dst_a,
                                                   int E, int CE,
                                                   const u8* __restrict__ histmat, const int* __restrict__ rowptr,
                                                   u16* __restrict__ srcs){
    __shared__ u32 lcnt[HW8];
    const int blk = blockIdx.x;
    const int i0 = blk*CE;
    const int i1 = min(i0+CE, E + N_NODES);
    const u8* __restrict__ pb = histmat + (size_t)blk*N_NODES;
    for (int w=threadIdx.x; w<HW8; w+=HTHREADS) lcnt[w]=0;
    __syncthreads();
    for (int i=i0+(int)threadIdx.x; i<i1; i+=HTHREADS){
        int s, d;
        if (i<E){ s=src_a[i]; d=dst_a[i]; } else { s=d=i-E; }
        u32 old = atomicAdd(&lcnt[d>>2], 1u<<((d&3)*8));
        u32 rank = (old >> ((d&3)*8)) & 0xFFu;
        int pos = rowptr[d] + (int)pb[d] + (int)rank;
        srcs[pos] = (u16)s;
    }
}

// ---------------------------------------------------------------- GEMM1 via MFMA: B (hi+lo) resident in LDS, A direct+prefetch
__global__ __launch_bounds__(G1_THR) void k_gemm1(
        const float* __restrict__ x,
        const u16* __restrict__ whiT, const u16* __restrict__ wloT,
        const float* __restrict__ att_src, const float* __restrict__ att_dst,
        u16* __restrict__ h1b, float* __restrict__ asrc, float* __restrict__ adst){
    __shared__ u16 Bh[D1*F_IN];   // 64 KB, XOR-swizzled [col][k]
    __shared__ u16 Bl[D1*F_IN];   // 64 KB
    const int tid = threadIdx.x;
    const int wid = tid>>6, l = tid&63;
    const int lq = l>>4, lr = l&15;

    for (int i = tid; i < (D1*F_IN)/8; i += G1_THR){
        int col = i >> 6;
        int c   = i & 63;
        int boff = (col*1024 + c*16) ^ ((col&7)<<4);
        *(uint4*)((char*)Bh + boff) = *(const uint4*)(whiT + (size_t)i*8);
        *(uint4*)((char*)Bl + boff) = *(const uint4*)(wloT + (size_t)i*8);
    }
    __syncthreads();

    const int wavebase = blockIdx.x*G1_ROWS + wid*16;
    const int arow = min(wavebase + lr, N_NODES-1);
    const float* __restrict__ xrow = x + (size_t)arow*F_IN + lq*8;

    f32x4 acc[4];
    #pragma unroll
    for (int n=0;n<4;n++) acc[n] = (f32x4){0.f,0.f,0.f,0.f};

    float4 p0 = *(const float4*)(xrow);
    float4 p1 = *(const float4*)(xrow+4);
    float4 p2 = *(const float4*)(xrow+32);
    float4 p3 = *(const float4*)(xrow+36);

    for (int ks=0; ks<8; ks++){
        bf16x8 ahi0, alo0, ahi1, alo1;
        cvt8(p0, p1, ahi0, alo0);
        cvt8(p2, p3, ahi1, alo1);
        if (ks < 7){
            const float* nx = xrow + (ks+1)*64;
            p0 = *(const float4*)(nx);
            p1 = *(const float4*)(nx+4);
            p2 = *(const float4*)(nx+32);
            p3 = *(const float4*)(nx+36);
        }
        const int k0 = ks*64;
        #pragma unroll
        for (int n=0;n<4;n++){
            const int colb = n*16 + lr;
            const int swz  = (colb&7)<<4;
            const int b0 = (colb*1024 + (k0 + lq*8)*2) ^ swz;
            const int b1 = (colb*1024 + (k0 + 32 + lq*8)*2) ^ swz;
            bf16x8 bhi0 = *(const bf16x8*)((const char*)Bh + b0);
            bf16x8 blo0 = *(const bf16x8*)((const char*)Bl + b0);
            acc[n] = __builtin_amdgcn_mfma_f32_16x16x32_bf16(ahi0, bhi0, acc[n], 0,0,0);
            acc[n] = __builtin_amdgcn_mfma_f32_16x16x32_bf16(ahi0, blo0, acc[n], 0,0,0);
            acc[n] = __builtin_amdgcn_mfma_f32_16x16x32_bf16(alo0, bhi0, acc[n], 0,0,0);
            bf16x8 bhi1 = *(const bf16x8*)((const char*)Bh + b1);
            bf16x8 blo1 = *(const bf16x8*)((const char*)Bl + b1);
            acc[n] = __builtin_amdgcn_mfma_f32_16x16x32_bf16(ahi1, bhi1, acc[n], 0,0,0);
            acc[n] = __builtin_amdgcn_mfma_f32_16x16x32_bf16(ahi1, blo1, acc[n], 0,0,0);
            acc[n] = __builtin_amdgcn_mfma_f32_16x16x32_bf16(alo1, bhi1, acc[n], 0,0,0);
        }
    }

    // epilogue: C/D layout col=lane&15, row=(lane>>4)*4+i  [HW-verified]
    #pragma unroll
    for (int n=0;n<4;n++){
        int col = n*16 + lr;
        float as_w = att_src[col], ad_w = att_dst[col];
        #pragma unroll
        for (int i=0;i<4;i++){
            int node = wavebase + lq*4 + i;
            float v = acc[n][i];
            float s = v*as_w, d = v*ad_w;
            s += __shfl_xor(s,1); d += __shfl_xor(d,1);
            s += __shfl_xor(s,2); d += __shfl_xor(d,2);
            s += __shfl_xor(s,4); d += __shfl_xor(d,4);
            if (node < N_NODES){
                h1b[(size_t)node*D1 + col] = f2bf(v);
                if ((l&7)==0){
                    int head = col>>3;
                    asrc[node*H1 + head] = s;
                    adst[node*H1 + head] = d;
                }
            }
        }
    }
}

// ---------------------------------------------------------------- layer1 aggregation: 8 edges per gather instruction
__global__ __launch_bounds__(256) void k_agg1(
        const int* __restrict__ rowptr, const u16* __restrict__ srcs,
        const float* __restrict__ asrc1, const float* __restrict__ adst1,
        const u16* __restrict__ h1b, float* __restrict__ out1){
    const int node = blockIdx.x*4 + (threadIdx.x>>6);
    const int lane = threadIdx.x & 63;
    const int g = lane >> 3;
    const int p = lane & 7;
    const int r0 = __builtin_amdgcn_readfirstlane(rowptr[node]);
    const int r1 = __builtin_amdgcn_readfirstlane(rowptr[node+1]);
    const float ad = adst1[node*H1 + p];
    float a0=0,a1=0,a2=0,a3=0,a4=0,a5=0,a6=0,a7=0, den=0;
    for (int base=r0; base<r1; base+=64){
        int eidx = base + lane;
        int sl = srcs[eidx < r1 ? eidx : (r1-1)];
        const int m = min(64, r1-base);
        for (int k=0; k*8 < m; k++){
            int e = k*8 + g;
            int s = __shfl(sl, e);
            float w = (base + e < r1) ? __expf(leaky(asrc1[s*H1 + p] + ad)) : 0.f;
            uint4 pv = *(const uint4*)(h1b + (size_t)s*D1 + p*8);
            a0 += w*bf2f((u16)(pv.x&0xFFFFu)); a1 += w*bf2f((u16)(pv.x>>16));
            a2 += w*bf2f((u16)(pv.y&0xFFFFu)); a3 += w*bf2f((u16)(pv.y>>16));
            a4 += w*bf2f((u16)(pv.z&0xFFFFu)); a5 += w*bf2f((u16)(pv.z>>16));
            a6 += w*bf2f((u16)(pv.w&0xFFFFu)); a7 += w*bf2f((u16)(pv.w>>16));
            den += w;
        }
    }
    #pragma unroll
    for (int off=8; off<64; off<<=1){
        a0 += __shfl_xor(a0,off); a1 += __shfl_xor(a1,off);
        a2 += __shfl_xor(a2,off); a3 += __shfl_xor(a3,off);
        a4 += __shfl_xor(a4,off); a5 += __shfl_xor(a5,off);
        a6 += __shfl_xor(a6,off); a7 += __shfl_xor(a7,off);
        den += __shfl_xor(den,off);
    }
    if (g == 0){
        float inv = 1.f/den;
        float* o = out1 + (size_t)node*D1 + p*8;
        *(float4*)(o)   = make_float4(a0*inv, a1*inv, a2*inv, a3*inv);
        *(float4*)(o+4) = make_float4(a4*inv, a5*inv, a6*inv, a7*inv);
    }
}

// ---------------------------------------------------------------- GEMM2 via MFMA: h2 = elu(out1+b1) @ W2 (+alpha epilogue); h2 stored bf16
__global__ __launch_bounds__(256) void k_gemm2(
        const float* __restrict__ out1, const float* __restrict__ b1,
        const u16* __restrict__ w2hiT, const u16* __restrict__ w2loT,
        const float* __restrict__ att_src2, const float* __restrict__ att_dst2,
        u16* __restrict__ h2b, float* __restrict__ asrc2, float* __restrict__ adst2){
    __shared__ u16 Ahi[64*64];   // 8 KB, XOR-swizzled
    __shared__ u16 Alo[64*64];   // 8 KB
    const int tid = threadIdx.x;
    const int wid = tid>>6, l = tid&63;
    const int lq = l>>4, lr = l&15;
    const int rowbase = blockIdx.x*64;

    #pragma unroll
    for (int q=0;q<4;q++){
        int p = tid + 256*q;
        int r = p>>4, kseg = p&15;
        int grow = min(rowbase + r, N_NODES-1);
        float4 v = *(const float4*)(out1 + (size_t)grow*D1 + kseg*4);
        float4 bb = *(const float4*)(b1 + kseg*4);
        float a0 = v.x+bb.x, a1 = v.y+bb.y, a2 = v.z+bb.z, a3 = v.w+bb.w;
        a0 = a0>0.f ? a0 : (__expf(a0)-1.f);
        a1 = a1>0.f ? a1 : (__expf(a1)-1.f);
        a2 = a2>0.f ? a2 : (__expf(a2)-1.f);
        a3 = a3>0.f ? a3 : (__expf(a3)-1.f);
        u16 h0=f2bf(a0), h1v=f2bf(a1), h2v=f2bf(a2), h3v=f2bf(a3);
        u16 e0=f2bf(a0-bf2f(h0)), e1=f2bf(a1-bf2f(h1v)),
            e2=f2bf(a2-bf2f(h2v)), e3=f2bf(a3-bf2f(h3v));
        int boff = (r*128 + kseg*8) ^ ((r&7)<<4);
        *(ushort4*)((char*)Ahi + boff) = make_ushort4(h0,h1v,h2v,h3v);
        *(ushort4*)((char*)Alo + boff) = make_ushort4(e0,e1,e2,e3);
    }
    __syncthreads();

    const int arow = wid*16 + lr;
    bf16x8 ahi[2], alo[2];
    #pragma unroll
    for (int kt=0;kt<2;kt++){
        int boff = (arow*128 + kt*64 + lq*16) ^ ((arow&7)<<4);
        ahi[kt] = *(const bf16x8*)((const char*)Ahi + boff);
        alo[kt] = *(const bf16x8*)((const char*)Alo + boff);
    }

    f32x4 acc[8];
    #pragma unroll
    for (int n=0;n<8;n++) acc[n] = (f32x4){0.f,0.f,0.f,0.f};
    #pragma unroll
    for (int n=0;n<8;n++){
        #pragma unroll
        for (int kt=0;kt<2;kt++){
            const size_t wo = (size_t)(n*16+lr)*D1 + kt*32 + lq*8;
            bf16x8 bhi = *(const bf16x8*)(w2hiT + wo);
            bf16x8 blo = *(const bf16x8*)(w2loT + wo);
            acc[n] = __builtin_amdgcn_mfma_f32_16x16x32_bf16(ahi[kt], bhi, acc[n], 0,0,0);
            acc[n] = __builtin_amdgcn_mfma_f32_16x16x32_bf16(ahi[kt], blo, acc[n], 0,0,0);
            acc[n] = __builtin_amdgcn_mfma_f32_16x16x32_bf16(alo[kt], bhi, acc[n], 0,0,0);
        }
    }

    float aw[8], dw[8];
    #pragma unroll
    for (int n=0;n<8;n++){ aw[n]=att_src2[n*16+lr]; dw[n]=att_dst2[n*16+lr]; }
    #pragma unroll
    for (int i=0;i<4;i++){
        int node = rowbase + wid*16 + lq*4 + i;
        bool ok = node < N_NODES;
        float s = 0.f, d = 0.f;
        #pragma unroll
        for (int n=0;n<8;n++){
            float v = acc[n][i];
            s = fmaf(v, aw[n], s);
            d = fmaf(v, dw[n], d);
            if (ok) h2b[(size_t)node*OUT_C + n*16 + lr] = f2bf(v);
        }
        s += __shfl_xor(s,1); d += __shfl_xor(d,1);
        s += __shfl_xor(s,2); d += __shfl_xor(d,2);
        s += __shfl_xor(s,4); d += __shfl_xor(d,4);
        s += __shfl_xor(s,8); d += __shfl_xor(d,8);
        if (ok && lr==0){ asrc2[node]=s; adst2[node]=d; }
    }
}

// ---------------------------------------------------------------- layer2 aggregation: 4 edges per gather instruction
__global__ __launch_bounds__(256) void k_agg2(
        const int* __restrict__ rowptr, const u16* __restrict__ srcs,
        const float* __restrict__ asrc2, const float* __restrict__ adst2,
        const u16* __restrict__ h2b, const float* __restrict__ b2,
        float* __restrict__ out){
    const int node = blockIdx.x*4 + (threadIdx.x>>6);
    const int lane = threadIdx.x & 63;
    const int g = lane >> 4;
    const int p = lane & 15;
    const int r0 = __builtin_amdgcn_readfirstlane(rowptr[node]);
    const int r1 = __builtin_amdgcn_readfirstlane(rowptr[node+1]);
    const float ad = adst2[node];
    float a0=0,a1=0,a2=0,a3=0,a4=0,a5=0,a6=0,a7=0, den=0;
    for (int base=r0; base<r1; base+=64){
        int eidx = base + lane;
        int sl = srcs[eidx < r1 ? eidx : (r1-1)];
        float wl = (eidx < r1) ? __expf(leaky(asrc2[sl] + ad)) : 0.f;
        const int m = min(64, r1-base);
        for (int k=0; k*4 < m; k++){
            int e = k*4 + g;
            int   s = __shfl(sl, e);
            float w = __shfl(wl, e);      // 0 for padded slots
            uint4 pv = *(const uint4*)(h2b + (size_t)s*OUT_C + p*8);
            a0 += w*bf2f((u16)(pv.x&0xFFFFu)); a1 += w*bf2f((u16)(pv.x>>16));
            a2 += w*bf2f((u16)(pv.y&0xFFFFu)); a3 += w*bf2f((u16)(pv.y>>16));
            a4 += w*bf2f((u16)(pv.z&0xFFFFu)); a5 += w*bf2f((u16)(pv.z>>16));
            a6 += w*bf2f((u16)(pv.w&0xFFFFu)); a7 += w*bf2f((u16)(pv.w>>16));
            den += w;
        }
    }
    #pragma unroll
    for (int off=16; off<64; off<<=1){
        a0 += __shfl_xor(a0,off); a1 += __shfl_xor(a1,off);
        a2 += __shfl_xor(a2,off); a3 += __shfl_xor(a3,off);
        a4 += __shfl_xor(a4,off); a5 += __shfl_xor(a5,off);
        a6 += __shfl_xor(a6,off); a7 += __shfl_xor(a7,off);
        den += __shfl_xor(den,off);
    }
    if (g == 0){
        float inv = 1.f/den;
        const float* bb = b2 + p*8;
        float* o = out + (size_t)node*OUT_C + p*8;
        *(float4*)(o)   = make_float4(a0*inv+bb[0], a1*inv+bb[1], a2*inv+bb[2], a3*inv+bb[3]);
        *(float4*)(o+4) = make_float4(a4*inv+bb[4], a5*inv+bb[5], a6*inv+bb[6], a7*inv+bb[7]);
    }
}

// ---------------------------------------------------------------- launch
extern "C" void kernel_launch(void* const* d_in, const int* in_sizes, int n_in,
                              void* d_out, int out_size, void* d_ws, size_t ws_size,
                              hipStream_t stream) {
    const float* x        = (const float*)d_in[0];
    const int*   edge     = (const int*)  d_in[1];
    const float* W1       = (const float*)d_in[2];
    const float* att_src1 = (const float*)d_in[3];
    const float* att_dst1 = (const float*)d_in[4];
    const float* b1       = (const float*)d_in[5];
    const float* W2       = (const float*)d_in[6];
    const float* att_src2 = (const float*)d_in[7];
    const float* att_dst2 = (const float*)d_in[8];
    const float* b2       = (const float*)d_in[9];
    float* out = (float*)d_out;

    const int E  = in_sizes[1] / 2;
    const int ET = E + N_NODES;
    const int CE = (ET + NHB - 1) / NHB;
    const int* src_a = edge;
    const int* dst_a = edge + E;

    // workspace layout
    float* ws = (float*)d_ws;
    float* h1f   = ws;                            // N*64 f32 region -> used as u16 h1b
    float* asrc1 = h1f   + (size_t)N_NODES*D1;    // N*8
    float* adst1 = asrc1 + (size_t)N_NODES*H1;    // N*8
    float* out1  = adst1 + (size_t)N_NODES*H1;    // N*64
    float* h2f   = out1  + (size_t)N_NODES*D1;    // N*128 f32 region -> used as u16 h2b
    float* asrc2 = h2f   + (size_t)N_NODES*OUT_C; // N
    float* adst2 = asrc2 + N_NODES;               // N
    int*   cnt    = (int*)(adst2 + N_NODES);      // N
    int*   rowptr = cnt    + N_NODES;             // N+4
    u16*   srcs   = (u16*)(rowptr + (N_NODES+4)); // ET u16
    int*   bsum   = (int*)(srcs + ((ET+3)&~3));   // 256 (8B-aligned)
    u8*    histmat= (u8*)(bsum + 256);            // NHB*N u8 (12.8 MB)
    u16*   whiT   = (u16*)(histmat + (size_t)NHB*N_NODES); // after histmat (no overlay)
    u16*   wloT   = whiT + F_IN*D1;
    u16*   w2hiT  = wloT + F_IN*D1;
    u16*   w2loT  = w2hiT + D1*OUT_C;
    u16*   h1b    = (u16*)h1f;
    u16*   h2b    = (u16*)h2f;

    // ---- CSR build (atomic-free counting sort, u8 histmat, single-pass LDS)
    hipLaunchKernelGGL(k_histB,   dim3(NHB), dim3(HTHREADS), 0, stream, dst_a, E, CE, histmat);
    hipLaunchKernelGGL(k_colscan, dim3(SNBLK), dim3(256), 0, stream, histmat, cnt, bsum);
    hipLaunchKernelGGL(k_scanC2,  dim3(SNBLK), dim3(256), 0, stream, cnt, bsum, rowptr,
                       W1, W2, whiT, wloT, w2hiT, w2loT);
    hipLaunchKernelGGL(k_scatterB,dim3(NHB), dim3(HTHREADS), 0, stream,
                       src_a, dst_a, E, CE, histmat, rowptr, srcs);

    // ---- layer 1
    hipLaunchKernelGGL(k_gemm1, dim3(NB1), dim3(G1_THR), 0, stream,
                       x, whiT, wloT, att_src1, att_dst1, h1b, asrc1, adst1);
    hipLaunchKernelGGL(k_agg1, dim3((N_NODES+3)/4), dim3(256), 0, stream,
                       rowptr, srcs, asrc1, adst1, h1b, out1);

    // ---- layer 2
    hipLaunchKernelGGL(k_gemm2, dim3((N_NODES+63)/64), dim3(256), 0, stream,
                       out1, b1, w2hiT, w2loT, att_src2, att_dst2, h2b, asrc2, adst2);
    hipLaunchKernelGGL(k_agg2, dim3((N_NODES+3)/4), dim3(256), 0, stream,
                       rowptr, srcs, asrc2, adst2, h2b, b2, out);
}